// Round 1
// baseline (3617.866 us; speedup 1.0000x reference)
//
#include <hip/hip_runtime.h>
#include <hip/hip_bf16.h>
#include <math.h>

// Problem constants (fixed by setup_inputs)
constexpr int B_ = 2;
constexpr int T_ = 2048;
constexpr int C_ = 1024;
constexpr int H_ = 16;
constexpr int D_ = 64;       // head dim
constexpr float SHIFT_ = 5.0f;
constexpr float P_MIN_ = 1e-4f;
constexpr float P_MAX_ = 1e3f;
constexpr float V_MIN_ = 1e-10f;

__device__ __forceinline__ float clamp_p(float pp) {
    float s = (pp >= 0.f) ? 1.f : -1.f;   // sign(sign(p)+0.5): >=0 -> +1, <0 -> -1
    return s * fminf(fmaxf(fabsf(pp), P_MIN_), P_MAX_);
}

// ---------------------------------------------------------------------------
// fp32 GEMM: C[M,N] = A[M,K] @ B[K,N] + bias[N]
// BM=BN=128, BK=16, 256 threads, 8x8 microtile per thread.
// M,N,K assumed divisible by tile dims (4096, 3072/1024, 1024 -> all fine).
// ---------------------------------------------------------------------------
__global__ __launch_bounds__(256)
void gemm_bias_128(const float* __restrict__ A, const float* __restrict__ Bm,
                   const float* __restrict__ bias, float* __restrict__ Cm,
                   int M, int N, int K) {
    __shared__ float As[16][128 + 4];   // [k][m], transposed on load
    __shared__ float Bs[16][128 + 4];   // [k][n]

    const int tid = threadIdx.x;
    const int tx = tid & 15;            // 0..15  (col group)
    const int ty = tid >> 4;            // 0..15  (row group)
    const int row0 = blockIdx.y * 128;
    const int col0 = blockIdx.x * 128;

    float acc[8][8] = {};

    for (int k0 = 0; k0 < K; k0 += 16) {
        // Load A tile: 128 rows x 16 k = 512 float4; 2 per thread.
#pragma unroll
        for (int i = 0; i < 2; ++i) {
            int idx = tid * 2 + i;          // 0..511
            int r   = idx >> 2;             // 0..127
            int kc  = (idx & 3) * 4;        // 0,4,8,12
            float4 av = *(const float4*)&A[(size_t)(row0 + r) * K + k0 + kc];
            As[kc + 0][r] = av.x;
            As[kc + 1][r] = av.y;
            As[kc + 2][r] = av.z;
            As[kc + 3][r] = av.w;
        }
        // Load B tile: 16 rows x 128 cols = 512 float4; 2 per thread.
#pragma unroll
        for (int i = 0; i < 2; ++i) {
            int idx = tid * 2 + i;
            int r   = idx >> 5;             // 0..15
            int cc  = (idx & 31) * 4;       // 0..124
            float4 bv = *(const float4*)&Bm[(size_t)(k0 + r) * N + col0 + cc];
            *(float4*)&Bs[r][cc] = bv;
        }
        __syncthreads();

#pragma unroll
        for (int kk = 0; kk < 16; ++kk) {
            float a[8], b[8];
            *(float4*)&a[0] = *(const float4*)&As[kk][ty * 8];
            *(float4*)&a[4] = *(const float4*)&As[kk][ty * 8 + 4];
            *(float4*)&b[0] = *(const float4*)&Bs[kk][tx * 8];
            *(float4*)&b[4] = *(const float4*)&Bs[kk][tx * 8 + 4];
#pragma unroll
            for (int i = 0; i < 8; ++i)
#pragma unroll
                for (int j = 0; j < 8; ++j)
                    acc[i][j] = fmaf(a[i], b[j], acc[i][j]);
        }
        __syncthreads();
    }

#pragma unroll
    for (int i = 0; i < 8; ++i) {
        int r = row0 + ty * 8 + i;
#pragma unroll
        for (int j = 0; j < 8; j += 4) {
            int cc = col0 + tx * 8 + j;
            float4 o;
            o.x = acc[i][j + 0] + bias[cc + 0];
            o.y = acc[i][j + 1] + bias[cc + 1];
            o.z = acc[i][j + 2] + bias[cc + 2];
            o.w = acc[i][j + 3] + bias[cc + 3];
            *(float4*)&Cm[(size_t)r * N + cc] = o;
        }
    }
}

// ---------------------------------------------------------------------------
// z_max[b,c] = max_t p_c * log(clip(|v[b,t,c]+5|, 1e-10))
// grid: B * (C/64) blocks, 256 threads = 64 cols x 4 row-chunks
// ---------------------------------------------------------------------------
__global__ __launch_bounds__(256)
void zmax_kernel(const float* __restrict__ qkv, const float* __restrict__ p_param,
                 float* __restrict__ zmax) {
    const int ctile = blockIdx.x & (C_ / 64 - 1);   // 0..15
    const int b = blockIdx.x >> 4;
    const int col = threadIdx.x & 63;
    const int r = threadIdx.x >> 6;                 // 0..3
    const int c = ctile * 64 + col;

    const float p = clamp_p(p_param[c]);
    const float* vp = qkv + (size_t)b * T_ * 3 * C_ + 2 * C_ + c;

    float lm = -INFINITY;
    for (int t = r; t < T_; t += 4) {
        float v = vp[(size_t)t * 3 * C_];
        float z = p * logf(fmaxf(fabsf(v + SHIFT_), V_MIN_));
        lm = fmaxf(lm, z);
    }
    __shared__ float red[4][64];
    red[r][col] = lm;
    __syncthreads();
    if (threadIdx.x < 64) {
        float m = fmaxf(fmaxf(red[0][threadIdx.x], red[1][threadIdx.x]),
                        fmaxf(red[2][threadIdx.x], red[3][threadIdx.x]));
        zmax[b * C_ + threadIdx.x + ctile * 64] = m;
    }
}

// ---------------------------------------------------------------------------
// In-place: v[b,t,c] <- exp(p_c*log(clip(|v+5|)) - zmax[b,c])
// ---------------------------------------------------------------------------
__global__ __launch_bounds__(256)
void vexp_kernel(float* __restrict__ qkv, const float* __restrict__ p_param,
                 const float* __restrict__ zmax) {
    int idx = blockIdx.x * 256 + threadIdx.x;       // 0 .. B*T*C-1
    int c = idx & (C_ - 1);
    int bt = idx >> 10;                             // /C
    int b = bt >> 11;                               // /T
    float p = clamp_p(p_param[c]);
    size_t addr = (size_t)bt * 3 * C_ + 2 * C_ + c;
    float v = qkv[addr];
    float z = p * logf(fmaxf(fabsf(v + SHIFT_), V_MIN_));
    qkv[addr] = expf(z - zmax[b * C_ + c]);
}

// ---------------------------------------------------------------------------
// Attention: one block per (b, h, q). Scores in LDS, 2-pass softmax, PV.
// mean[b, q, h*D + dim]
// ---------------------------------------------------------------------------
__global__ __launch_bounds__(256)
void attn_kernel(const float* __restrict__ qkv, float* __restrict__ mean) {
    const int q_idx = blockIdx.x & (T_ - 1);
    const int h = (blockIdx.x >> 11) & (H_ - 1);
    const int b = blockIdx.x >> 15;

    __shared__ float s[T_];        // scores -> att weights
    __shared__ float qs[D_];
    __shared__ float red[256];
    __shared__ float pv[4][D_];

    const int tid = threadIdx.x;
    const size_t base = (size_t)b * T_ * 3 * C_;
    const float* qp = qkv + base + (size_t)q_idx * 3 * C_ + h * D_;
    const float* kp = qkv + base + C_ + h * D_;
    const float* vp = qkv + base + 2 * C_ + h * D_;

    if (tid < D_) qs[tid] = qp[tid];
    __syncthreads();

    const int nk = q_idx + 1;
    float lmax = -INFINITY;
    for (int j = tid; j < nk; j += 256) {
        const float* kr = kp + (size_t)j * 3 * C_;
        float dot = 0.f;
#pragma unroll
        for (int cc = 0; cc < D_; cc += 4) {
            float4 k4 = *(const float4*)&kr[cc];
            dot = fmaf(qs[cc + 0], k4.x, dot);
            dot = fmaf(qs[cc + 1], k4.y, dot);
            dot = fmaf(qs[cc + 2], k4.z, dot);
            dot = fmaf(qs[cc + 3], k4.w, dot);
        }
        dot *= 0.125f;              // 1/sqrt(64)
        s[j] = dot;
        lmax = fmaxf(lmax, dot);
    }
    // block-reduce max
    red[tid] = lmax;
    __syncthreads();
    for (int st = 128; st > 0; st >>= 1) {
        if (tid < st) red[tid] = fmaxf(red[tid], red[tid + st]);
        __syncthreads();
    }
    const float m = red[0];
    __syncthreads();                // everyone has read red[0] before reuse

    float lsum = 0.f;
    for (int j = tid; j < nk; j += 256) {
        float e = expf(s[j] - m);
        s[j] = e;
        lsum += e;
    }
    red[tid] = lsum;
    __syncthreads();
    for (int st = 128; st > 0; st >>= 1) {
        if (tid < st) red[tid] += red[tid + st];
        __syncthreads();
    }
    const float denom = red[0];

    // PV: dim = tid&63 over 4 key-segments; coalesced v reads
    const int dim = tid & 63;
    const int seg = tid >> 6;
    float acc = 0.f;
    for (int j = seg; j < nk; j += 4)
        acc = fmaf(s[j], vp[(size_t)j * 3 * C_ + dim], acc);
    pv[seg][dim] = acc;
    __syncthreads();
    if (tid < 64) {
        float o = (pv[0][tid] + pv[1][tid] + pv[2][tid] + pv[3][tid]) / denom;
        mean[((size_t)(b * T_ + q_idx)) * C_ + h * D_ + tid] = o;
    }
}

// ---------------------------------------------------------------------------
// In-place inverse transform: y = exp((zmax + log(mean))/p) - 5
// ---------------------------------------------------------------------------
__global__ __launch_bounds__(256)
void y_kernel(float* __restrict__ mean, const float* __restrict__ p_param,
              const float* __restrict__ zmax) {
    int idx = blockIdx.x * 256 + threadIdx.x;
    int c = idx & (C_ - 1);
    int bt = idx >> 10;
    int b = bt >> 11;
    float p = clamp_p(p_param[c]);
    float mval = mean[idx];
    float y = expf((zmax[b * C_ + c] + logf(mval)) / p) - SHIFT_;
    mean[idx] = y;
}

// ---------------------------------------------------------------------------
extern "C" void kernel_launch(void* const* d_in, const int* in_sizes, int n_in,
                              void* d_out, int out_size, void* d_ws, size_t ws_size,
                              hipStream_t stream) {
    const float* x      = (const float*)d_in[0];
    const float* w_attn = (const float*)d_in[1];
    const float* b_attn = (const float*)d_in[2];
    const float* w_proj = (const float*)d_in[3];
    const float* b_proj = (const float*)d_in[4];
    const float* p_par  = (const float*)d_in[5];
    float* out = (float*)d_out;

    char* ws = (char*)d_ws;
    float* qkv  = (float*)ws;                                           // B*T*3C
    float* mean = (float*)(ws + (size_t)B_ * T_ * 3 * C_ * sizeof(float));
    float* zmax = (float*)(ws + (size_t)B_ * T_ * 3 * C_ * sizeof(float)
                              + (size_t)B_ * T_ * C_ * sizeof(float));  // B*C

    // 1) qkv = x @ w_attn + b_attn   [4096 x 3072]
    dim3 g1(3 * C_ / 128, (B_ * T_) / 128);
    gemm_bias_128<<<g1, 256, 0, stream>>>(x, w_attn, b_attn, qkv,
                                          B_ * T_, 3 * C_, C_);
    // 2) z_max over T per (b,c)
    zmax_kernel<<<B_ * (C_ / 64), 256, 0, stream>>>(qkv, p_par, zmax);
    // 3) v <- exp(z - zmax) in-place
    vexp_kernel<<<B_ * T_ * C_ / 256, 256, 0, stream>>>(qkv, p_par, zmax);
    // 4) attention -> mean
    attn_kernel<<<B_ * H_ * T_, 256, 0, stream>>>(qkv, mean);
    // 5) y = exp((zmax + log mean)/p) - 5, in-place
    y_kernel<<<B_ * T_ * C_ / 256, 256, 0, stream>>>(mean, p_par, zmax);
    // 6) out = y @ w_proj + b_proj   [4096 x 1024]
    dim3 g2(C_ / 128, (B_ * T_) / 128);
    gemm_bias_128<<<g2, 256, 0, stream>>>(mean, w_proj, b_proj, out,
                                          B_ * T_, C_, C_);
}

// Round 2
// 2408.358 us; speedup vs baseline: 1.5022x; 1.5022x over previous
//
#include <hip/hip_runtime.h>
#include <hip/hip_bf16.h>
#include <math.h>

// Problem constants (fixed by setup_inputs)
constexpr int B_ = 2;
constexpr int T_ = 2048;
constexpr int C_ = 1024;
constexpr int H_ = 16;
constexpr int D_ = 64;       // head dim
constexpr float SHIFT_ = 5.0f;
constexpr float P_MIN_ = 1e-4f;
constexpr float P_MAX_ = 1e3f;
constexpr float V_MIN_ = 1e-10f;

__device__ __forceinline__ float clamp_p(float pp) {
    float s = (pp >= 0.f) ? 1.f : -1.f;   // sign(sign(p)+0.5): >=0 -> +1, <0 -> -1
    return s * fminf(fmaxf(fabsf(pp), P_MIN_), P_MAX_);
}

// ---------------------------------------------------------------------------
// fp32 GEMM: C[M,N] = A[M,K] @ B[K,N] + bias[N]
// BM=BN=128, BK=16, 256 threads, 8x8 microtile per thread.
// ---------------------------------------------------------------------------
__global__ __launch_bounds__(256)
void gemm_bias_128(const float* __restrict__ A, const float* __restrict__ Bm,
                   const float* __restrict__ bias, float* __restrict__ Cm,
                   int M, int N, int K) {
    __shared__ float As[16][128 + 4];   // [k][m], transposed on load
    __shared__ float Bs[16][128 + 4];   // [k][n]

    const int tid = threadIdx.x;
    const int tx = tid & 15;            // 0..15  (col group)
    const int ty = tid >> 4;            // 0..15  (row group)
    const int row0 = blockIdx.y * 128;
    const int col0 = blockIdx.x * 128;

    float acc[8][8] = {};

    for (int k0 = 0; k0 < K; k0 += 16) {
#pragma unroll
        for (int i = 0; i < 2; ++i) {
            int idx = tid * 2 + i;          // 0..511
            int r   = idx >> 2;             // 0..127
            int kc  = (idx & 3) * 4;        // 0,4,8,12
            float4 av = *(const float4*)&A[(size_t)(row0 + r) * K + k0 + kc];
            As[kc + 0][r] = av.x;
            As[kc + 1][r] = av.y;
            As[kc + 2][r] = av.z;
            As[kc + 3][r] = av.w;
        }
#pragma unroll
        for (int i = 0; i < 2; ++i) {
            int idx = tid * 2 + i;
            int r   = idx >> 5;             // 0..15
            int cc  = (idx & 31) * 4;       // 0..124
            float4 bv = *(const float4*)&Bm[(size_t)(k0 + r) * N + col0 + cc];
            *(float4*)&Bs[r][cc] = bv;
        }
        __syncthreads();

#pragma unroll
        for (int kk = 0; kk < 16; ++kk) {
            float a[8], b[8];
            *(float4*)&a[0] = *(const float4*)&As[kk][ty * 8];
            *(float4*)&a[4] = *(const float4*)&As[kk][ty * 8 + 4];
            *(float4*)&b[0] = *(const float4*)&Bs[kk][tx * 8];
            *(float4*)&b[4] = *(const float4*)&Bs[kk][tx * 8 + 4];
#pragma unroll
            for (int i = 0; i < 8; ++i)
#pragma unroll
                for (int j = 0; j < 8; ++j)
                    acc[i][j] = fmaf(a[i], b[j], acc[i][j]);
        }
        __syncthreads();
    }

#pragma unroll
    for (int i = 0; i < 8; ++i) {
        int r = row0 + ty * 8 + i;
#pragma unroll
        for (int j = 0; j < 8; j += 4) {
            int cc = col0 + tx * 8 + j;
            float4 o;
            o.x = acc[i][j + 0] + bias[cc + 0];
            o.y = acc[i][j + 1] + bias[cc + 1];
            o.z = acc[i][j + 2] + bias[cc + 2];
            o.w = acc[i][j + 3] + bias[cc + 3];
            *(float4*)&Cm[(size_t)r * N + cc] = o;
        }
    }
}

// ---------------------------------------------------------------------------
// z_max[b,c] = max_t p_c * log(clip(|v[b,t,c]+5|, 1e-10))
// ---------------------------------------------------------------------------
__global__ __launch_bounds__(256)
void zmax_kernel(const float* __restrict__ qkv, const float* __restrict__ p_param,
                 float* __restrict__ zmax) {
    const int ctile = blockIdx.x & (C_ / 64 - 1);   // 0..15
    const int b = blockIdx.x >> 4;
    const int col = threadIdx.x & 63;
    const int r = threadIdx.x >> 6;                 // 0..3
    const int c = ctile * 64 + col;

    const float p = clamp_p(p_param[c]);
    const float* vp = qkv + (size_t)b * T_ * 3 * C_ + 2 * C_ + c;

    float lm = -INFINITY;
    for (int t = r; t < T_; t += 4) {
        float v = vp[(size_t)t * 3 * C_];
        float z = p * logf(fmaxf(fabsf(v + SHIFT_), V_MIN_));
        lm = fmaxf(lm, z);
    }
    __shared__ float red[4][64];
    red[r][col] = lm;
    __syncthreads();
    if (threadIdx.x < 64) {
        float m = fmaxf(fmaxf(red[0][threadIdx.x], red[1][threadIdx.x]),
                        fmaxf(red[2][threadIdx.x], red[3][threadIdx.x]));
        zmax[b * C_ + threadIdx.x + ctile * 64] = m;
    }
}

// ---------------------------------------------------------------------------
// In-place: v[b,t,c] <- exp(p_c*log(clip(|v+5|)) - zmax[b,c])
// ---------------------------------------------------------------------------
__global__ __launch_bounds__(256)
void vexp_kernel(float* __restrict__ qkv, const float* __restrict__ p_param,
                 const float* __restrict__ zmax) {
    int idx = blockIdx.x * 256 + threadIdx.x;       // 0 .. B*T*C-1
    int c = idx & (C_ - 1);
    int bt = idx >> 10;                             // /C
    int b = bt >> 11;                               // /T
    float p = clamp_p(p_param[c]);
    size_t addr = (size_t)bt * 3 * C_ + 2 * C_ + c;
    float v = qkv[addr];
    float z = p * logf(fmaxf(fabsf(v + SHIFT_), V_MIN_));
    qkv[addr] = expf(z - zmax[b * C_ + c]);
}

// ---------------------------------------------------------------------------
// Flash attention, fp32 SIMT. One wave (64 threads) per block.
// Q-tile 64 x K-tile 64, 8x8 microtile/thread, online softmax.
// LDS: Qs, KPs (K aliased with P), Vs; row stride 68 floats (16B aligned),
// XOR swizzle group^=(row>>3) to spread fragment-read banks.
// Single wave -> DS ops in order -> no barriers at all.
// ---------------------------------------------------------------------------
__device__ __forceinline__ int sw(int row, int g) {
    return row * 68 + (((g) ^ (row >> 3)) << 2);    // float offset of 16B group
}

__global__ __launch_bounds__(64, 1)
void attn_flash(const float* __restrict__ qkv, float* __restrict__ mean) {
    __shared__ float Qs[64 * 68];
    __shared__ float KPs[64 * 68];   // K tile, later aliased by P
    __shared__ float Vs[64 * 68];

    const int tid = threadIdx.x;
    const int tx = tid & 7;          // S-col / O-col group
    const int ty = tid >> 3;         // S-row / O-row group

    const int bh = blockIdx.x >> 5;
    const int qt = 31 - (blockIdx.x & 31);   // heavy tiles first
    const int b = bh >> 4;
    const int h = bh & 15;
    const int q0 = qt * 64;

    const size_t base = (size_t)b * T_ * 3 * C_;
    const float* qbase = qkv + base + (size_t)q0 * 3 * C_ + h * D_;
    const float* kbase = qkv + base + C_ + h * D_;
    const float* vbase = qkv + base + 2 * C_ + h * D_;

    // load Q tile (64 rows x 16 float4)
#pragma unroll
    for (int it = 0; it < 16; ++it) {
        int idx = tid + 64 * it;
        int row = idx >> 4, g = idx & 15;
        float4 qv = *(const float4*)&qbase[(size_t)row * (3 * C_) + g * 4];
        *(float4*)&Qs[sw(row, g)] = qv;
    }

    float O[8][8] = {};
    float m_i[8], l_i[8];
#pragma unroll
    for (int i = 0; i < 8; ++i) { m_i[i] = -INFINITY; l_i[i] = 0.f; }

    for (int kt = 0; kt <= qt; ++kt) {
        const float* kb = kbase + (size_t)(kt * 64) * (3 * C_);
        const float* vb = vbase + (size_t)(kt * 64) * (3 * C_);
        // load K,V tiles
#pragma unroll
        for (int it = 0; it < 16; ++it) {
            int idx = tid + 64 * it;
            int row = idx >> 4, g = idx & 15;
            float4 kv = *(const float4*)&kb[(size_t)row * (3 * C_) + g * 4];
            float4 vv = *(const float4*)&vb[(size_t)row * (3 * C_) + g * 4];
            *(float4*)&KPs[sw(row, g)] = kv;
            *(float4*)&Vs[sw(row, g)] = vv;
        }

        // S = Q K^T  (8x8 per thread, k-dim 64)
        float s[8][8] = {};
#pragma unroll
        for (int k4 = 0; k4 < 16; ++k4) {
            float4 qv[8];
#pragma unroll
            for (int i = 0; i < 8; ++i)
                qv[i] = *(const float4*)&Qs[sw(ty * 8 + i, k4)];
#pragma unroll
            for (int j = 0; j < 8; ++j) {
                float4 kv = *(const float4*)&KPs[sw(tx * 8 + j, k4)];
#pragma unroll
                for (int i = 0; i < 8; ++i) {
                    s[i][j] = fmaf(qv[i].x, kv.x, s[i][j]);
                    s[i][j] = fmaf(qv[i].y, kv.y, s[i][j]);
                    s[i][j] = fmaf(qv[i].z, kv.z, s[i][j]);
                    s[i][j] = fmaf(qv[i].w, kv.w, s[i][j]);
                }
            }
        }

        // scale + causal mask (diag tile only)
        if (kt == qt) {
#pragma unroll
            for (int i = 0; i < 8; ++i)
#pragma unroll
                for (int j = 0; j < 8; ++j)
                    s[i][j] = (tx * 8 + j > ty * 8 + i) ? -INFINITY
                                                        : s[i][j] * 0.125f;
        } else {
#pragma unroll
            for (int i = 0; i < 8; ++i)
#pragma unroll
                for (int j = 0; j < 8; ++j)
                    s[i][j] *= 0.125f;
        }

        // online softmax; write P into KPs (K dead; single wave, DS in-order)
#pragma unroll
        for (int i = 0; i < 8; ++i) {
            float rm = s[i][0];
#pragma unroll
            for (int j = 1; j < 8; ++j) rm = fmaxf(rm, s[i][j]);
            rm = fmaxf(rm, __shfl_xor(rm, 1));
            rm = fmaxf(rm, __shfl_xor(rm, 2));
            rm = fmaxf(rm, __shfl_xor(rm, 4));
            float mnew = fmaxf(m_i[i], rm);
            float sc = __expf(m_i[i] - mnew);
            m_i[i] = mnew;
            float p[8], rs = 0.f;
#pragma unroll
            for (int j = 0; j < 8; ++j) { p[j] = __expf(s[i][j] - mnew); rs += p[j]; }
            rs += __shfl_xor(rs, 1);
            rs += __shfl_xor(rs, 2);
            rs += __shfl_xor(rs, 4);
            l_i[i] = l_i[i] * sc + rs;
#pragma unroll
            for (int j = 0; j < 8; ++j) O[i][j] *= sc;
            float4 p0 = {p[0], p[1], p[2], p[3]};
            float4 p1 = {p[4], p[5], p[6], p[7]};
            *(float4*)&KPs[sw(ty * 8 + i, tx * 2)] = p0;
            *(float4*)&KPs[sw(ty * 8 + i, tx * 2 + 1)] = p1;
        }

        // O += P V   (P rows ty*8+i, V cols tx*8+j)
#pragma unroll
        for (int k4 = 0; k4 < 16; ++k4) {
            float4 pv[8];
#pragma unroll
            for (int i = 0; i < 8; ++i)
                pv[i] = *(const float4*)&KPs[sw(ty * 8 + i, k4)];
#pragma unroll
            for (int u = 0; u < 4; ++u) {
                int krow = k4 * 4 + u;
                float4 v0 = *(const float4*)&Vs[sw(krow, tx * 2)];
                float4 v1 = *(const float4*)&Vs[sw(krow, tx * 2 + 1)];
#pragma unroll
                for (int i = 0; i < 8; ++i) {
                    float pk = (u == 0) ? pv[i].x : (u == 1) ? pv[i].y
                             : (u == 2) ? pv[i].z : pv[i].w;
                    O[i][0] = fmaf(pk, v0.x, O[i][0]);
                    O[i][1] = fmaf(pk, v0.y, O[i][1]);
                    O[i][2] = fmaf(pk, v0.z, O[i][2]);
                    O[i][3] = fmaf(pk, v0.w, O[i][3]);
                    O[i][4] = fmaf(pk, v1.x, O[i][4]);
                    O[i][5] = fmaf(pk, v1.y, O[i][5]);
                    O[i][6] = fmaf(pk, v1.z, O[i][6]);
                    O[i][7] = fmaf(pk, v1.w, O[i][7]);
                }
            }
        }
    }

    // normalize + store
#pragma unroll
    for (int i = 0; i < 8; ++i) {
        float inv = 1.f / l_i[i];
        float4 o0 = {O[i][0] * inv, O[i][1] * inv, O[i][2] * inv, O[i][3] * inv};
        float4 o1 = {O[i][4] * inv, O[i][5] * inv, O[i][6] * inv, O[i][7] * inv};
        size_t rowa = ((size_t)(b * T_ + q0 + ty * 8 + i)) * C_ + h * D_ + tx * 8;
        *(float4*)&mean[rowa] = o0;
        *(float4*)&mean[rowa + 4] = o1;
    }
}

// ---------------------------------------------------------------------------
// In-place inverse transform: y = exp((zmax + log(mean))/p) - 5
// ---------------------------------------------------------------------------
__global__ __launch_bounds__(256)
void y_kernel(float* __restrict__ mean, const float* __restrict__ p_param,
              const float* __restrict__ zmax) {
    int idx = blockIdx.x * 256 + threadIdx.x;
    int c = idx & (C_ - 1);
    int bt = idx >> 10;
    int b = bt >> 11;
    float p = clamp_p(p_param[c]);
    float mval = mean[idx];
    float y = expf((zmax[b * C_ + c] + logf(mval)) / p) - SHIFT_;
    mean[idx] = y;
}

// ---------------------------------------------------------------------------
extern "C" void kernel_launch(void* const* d_in, const int* in_sizes, int n_in,
                              void* d_out, int out_size, void* d_ws, size_t ws_size,
                              hipStream_t stream) {
    const float* x      = (const float*)d_in[0];
    const float* w_attn = (const float*)d_in[1];
    const float* b_attn = (const float*)d_in[2];
    const float* w_proj = (const float*)d_in[3];
    const float* b_proj = (const float*)d_in[4];
    const float* p_par  = (const float*)d_in[5];
    float* out = (float*)d_out;

    char* ws = (char*)d_ws;
    float* qkv  = (float*)ws;                                           // B*T*3C
    float* mean = (float*)(ws + (size_t)B_ * T_ * 3 * C_ * sizeof(float));
    float* zmax = (float*)(ws + (size_t)B_ * T_ * 3 * C_ * sizeof(float)
                              + (size_t)B_ * T_ * C_ * sizeof(float));  // B*C

    // 1) qkv = x @ w_attn + b_attn   [4096 x 3072]
    dim3 g1(3 * C_ / 128, (B_ * T_) / 128);
    gemm_bias_128<<<g1, 256, 0, stream>>>(x, w_attn, b_attn, qkv,
                                          B_ * T_, 3 * C_, C_);
    // 2) z_max over T per (b,c)
    zmax_kernel<<<B_ * (C_ / 64), 256, 0, stream>>>(qkv, p_par, zmax);
    // 3) v <- exp(z - zmax) in-place
    vexp_kernel<<<B_ * T_ * C_ / 256, 256, 0, stream>>>(qkv, p_par, zmax);
    // 4) flash attention -> mean
    attn_flash<<<B_ * H_ * (T_ / 64), 64, 0, stream>>>(qkv, mean);
    // 5) y = exp((zmax + log mean)/p) - 5, in-place
    y_kernel<<<B_ * T_ * C_ / 256, 256, 0, stream>>>(mean, p_par, zmax);
    // 6) out = y @ w_proj + b_proj   [4096 x 1024]
    dim3 g2(C_ / 128, (B_ * T_) / 128);
    gemm_bias_128<<<g2, 256, 0, stream>>>(mean, w_proj, b_proj, out,
                                          B_ * T_, C_, C_);
}

// Round 3
// 813.970 us; speedup vs baseline: 4.4447x; 2.9588x over previous
//
#include <hip/hip_runtime.h>
#include <hip/hip_bf16.h>
#include <math.h>

// Problem constants (fixed by setup_inputs)
constexpr int B_ = 2;
constexpr int T_ = 2048;
constexpr int C_ = 1024;
constexpr int H_ = 16;
constexpr int D_ = 64;       // head dim
constexpr float SHIFT_ = 5.0f;
constexpr float P_MIN_ = 1e-4f;
constexpr float P_MAX_ = 1e3f;
constexpr float V_MIN_ = 1e-10f;

typedef __attribute__((ext_vector_type(8))) short s16x8;
typedef __attribute__((ext_vector_type(4))) float f32x4;

__device__ __forceinline__ float clamp_p(float pp) {
    float s = (pp >= 0.f) ? 1.f : -1.f;
    return s * fminf(fmaxf(fabsf(pp), P_MIN_), P_MAX_);
}

// round-to-nearest-even fp32 -> bf16 bits
__device__ __forceinline__ unsigned short f2bf(float f) {
    unsigned int u = __float_as_uint(f);
    u += 0x7fffu + ((u >> 16) & 1u);
    return (unsigned short)(u >> 16);
}

// ---------------------------------------------------------------------------
// fp32 GEMM: C[M,N] = A[M,K] @ B[K,N] + bias[N]  (unchanged from R1)
// ---------------------------------------------------------------------------
__global__ __launch_bounds__(256)
void gemm_bias_128(const float* __restrict__ A, const float* __restrict__ Bm,
                   const float* __restrict__ bias, float* __restrict__ Cm,
                   int M, int N, int K) {
    __shared__ float As[16][128 + 4];
    __shared__ float Bs[16][128 + 4];

    const int tid = threadIdx.x;
    const int tx = tid & 15;
    const int ty = tid >> 4;
    const int row0 = blockIdx.y * 128;
    const int col0 = blockIdx.x * 128;

    float acc[8][8] = {};

    for (int k0 = 0; k0 < K; k0 += 16) {
#pragma unroll
        for (int i = 0; i < 2; ++i) {
            int idx = tid * 2 + i;
            int r   = idx >> 2;
            int kc  = (idx & 3) * 4;
            float4 av = *(const float4*)&A[(size_t)(row0 + r) * K + k0 + kc];
            As[kc + 0][r] = av.x;
            As[kc + 1][r] = av.y;
            As[kc + 2][r] = av.z;
            As[kc + 3][r] = av.w;
        }
#pragma unroll
        for (int i = 0; i < 2; ++i) {
            int idx = tid * 2 + i;
            int r   = idx >> 5;
            int cc  = (idx & 31) * 4;
            float4 bv = *(const float4*)&Bm[(size_t)(k0 + r) * N + col0 + cc];
            *(float4*)&Bs[r][cc] = bv;
        }
        __syncthreads();

#pragma unroll
        for (int kk = 0; kk < 16; ++kk) {
            float a[8], b[8];
            *(float4*)&a[0] = *(const float4*)&As[kk][ty * 8];
            *(float4*)&a[4] = *(const float4*)&As[kk][ty * 8 + 4];
            *(float4*)&b[0] = *(const float4*)&Bs[kk][tx * 8];
            *(float4*)&b[4] = *(const float4*)&Bs[kk][tx * 8 + 4];
#pragma unroll
            for (int i = 0; i < 8; ++i)
#pragma unroll
                for (int j = 0; j < 8; ++j)
                    acc[i][j] = fmaf(a[i], b[j], acc[i][j]);
        }
        __syncthreads();
    }

#pragma unroll
    for (int i = 0; i < 8; ++i) {
        int r = row0 + ty * 8 + i;
#pragma unroll
        for (int j = 0; j < 8; j += 4) {
            int cc = col0 + tx * 8 + j;
            float4 o;
            o.x = acc[i][j + 0] + bias[cc + 0];
            o.y = acc[i][j + 1] + bias[cc + 1];
            o.z = acc[i][j + 2] + bias[cc + 2];
            o.w = acc[i][j + 3] + bias[cc + 3];
            *(float4*)&Cm[(size_t)r * N + cc] = o;
        }
    }
}

// ---------------------------------------------------------------------------
// z_max[b,c] = max_t p_c * log(clip(|v[b,t,c]+5|, 1e-10))
// ---------------------------------------------------------------------------
__global__ __launch_bounds__(256)
void zmax_kernel(const float* __restrict__ qkv, const float* __restrict__ p_param,
                 float* __restrict__ zmax) {
    const int ctile = blockIdx.x & (C_ / 64 - 1);
    const int b = blockIdx.x >> 4;
    const int col = threadIdx.x & 63;
    const int r = threadIdx.x >> 6;
    const int c = ctile * 64 + col;

    const float p = clamp_p(p_param[c]);
    const float* vp = qkv + (size_t)b * T_ * 3 * C_ + 2 * C_ + c;

    float lm = -INFINITY;
    for (int t = r; t < T_; t += 4) {
        float v = vp[(size_t)t * 3 * C_];
        float z = p * logf(fmaxf(fabsf(v + SHIFT_), V_MIN_));
        lm = fmaxf(lm, z);
    }
    __shared__ float red[4][64];
    red[r][col] = lm;
    __syncthreads();
    if (threadIdx.x < 64) {
        float m = fmaxf(fmaxf(red[0][threadIdx.x], red[1][threadIdx.x]),
                        fmaxf(red[2][threadIdx.x], red[3][threadIdx.x]));
        zmax[b * C_ + threadIdx.x + ctile * 64] = m;
    }
}

// ---------------------------------------------------------------------------
// In-place: v[b,t,c] <- exp(p_c*log(clip(|v+5|)) - zmax[b,c])
// ---------------------------------------------------------------------------
__global__ __launch_bounds__(256)
void vexp_kernel(float* __restrict__ qkv, const float* __restrict__ p_param,
                 const float* __restrict__ zmax) {
    int idx = blockIdx.x * 256 + threadIdx.x;
    int c = idx & (C_ - 1);
    int bt = idx >> 10;
    int b = bt >> 11;
    float p = clamp_p(p_param[c]);
    size_t addr = (size_t)bt * 3 * C_ + 2 * C_ + c;
    float v = qkv[addr];
    float z = p * logf(fmaxf(fabsf(v + SHIFT_), V_MIN_));
    qkv[addr] = expf(z - zmax[b * C_ + c]);
}

// ---------------------------------------------------------------------------
// Flash attention, bf16 MFMA (16x16x32), fp32 accumulate.
// Block = 256 threads (4 waves). Q-tile 64 (16 rows/wave), K-tile 64.
// Layouts (verified per guide):
//   A-frag: A[m=lane&15][k=quad*8+j]   B-frag: B[k=quad*8+j][n=lane&15]
//   C/D  : col=lane&15, row=quad*4+reg
// Ks row-major feeds QK^T B-frags (S=Q K^T contracts over d).
// Vt = V transposed at staging feeds PV B-frags (contracts over t).
// P round-trips through per-wave LDS buffer (C-layout -> A-layout).
// LDS = 36864 B -> 4 blocks/CU -> 16 waves/CU.
// ---------------------------------------------------------------------------
__global__ __launch_bounds__(256)
void attn_mfma(const float* __restrict__ qkv, float* __restrict__ mean) {
    __shared__ unsigned short Qs[64 * 72];
    __shared__ unsigned short Ks[64 * 72];
    __shared__ unsigned short Vt[64 * 72];   // Vt[d][t]
    __shared__ unsigned short Ps[4][16 * 72];

    const int tid = threadIdx.x;
    const int w = tid >> 6;
    const int lane = tid & 63;
    const int l16 = lane & 15;
    const int quad = lane >> 4;

    const int bh = blockIdx.x >> 5;
    const int qt = 31 - (blockIdx.x & 31);   // heavy tiles first
    const int b = bh >> 4;
    const int h = bh & 15;
    const int q0 = qt * 64;

    const size_t base = (size_t)b * T_ * 3 * C_;
    const float* qbase = qkv + base + (size_t)q0 * 3 * C_ + h * D_;
    const float* kbase = qkv + base + C_ + h * D_;
    const float* vbase = qkv + base + 2 * C_ + h * D_;

    // stage Q tile: thread -> row t=tid>>2, 16 cols from (tid&3)*16
    {
        const int t = tid >> 2, c0 = (tid & 3) * 16;
        const float* src = qbase + (size_t)t * (3 * C_) + c0;
        unsigned short tmp[16];
#pragma unroll
        for (int u = 0; u < 16; u += 4) {
            float4 f = *(const float4*)&src[u];
            tmp[u + 0] = f2bf(f.x); tmp[u + 1] = f2bf(f.y);
            tmp[u + 2] = f2bf(f.z); tmp[u + 3] = f2bf(f.w);
        }
        *(s16x8*)&Qs[t * 72 + c0]     = *(s16x8*)&tmp[0];
        *(s16x8*)&Qs[t * 72 + c0 + 8] = *(s16x8*)&tmp[8];
    }

    f32x4 O[4] = {};                 // O[nt][reg] ; reg r -> row quad*4+r
    float m_i[4], l_i[4];
#pragma unroll
    for (int r = 0; r < 4; ++r) { m_i[r] = -INFINITY; l_i[r] = 0.f; }

    for (int kt = 0; kt <= qt; ++kt) {
        __syncthreads();             // protect Ks/Vt from prior-iter readers
        {
            const int t = tid >> 2, c0 = (tid & 3) * 16;
            const float* ksrc = kbase + (size_t)(kt * 64 + t) * (3 * C_) + c0;
            const float* vsrc = vbase + (size_t)(kt * 64 + t) * (3 * C_) + c0;
            unsigned short tk[16];
#pragma unroll
            for (int u = 0; u < 16; u += 4) {
                float4 f = *(const float4*)&ksrc[u];
                tk[u + 0] = f2bf(f.x); tk[u + 1] = f2bf(f.y);
                tk[u + 2] = f2bf(f.z); tk[u + 3] = f2bf(f.w);
            }
            *(s16x8*)&Ks[t * 72 + c0]     = *(s16x8*)&tk[0];
            *(s16x8*)&Ks[t * 72 + c0 + 8] = *(s16x8*)&tk[8];
#pragma unroll
            for (int u = 0; u < 16; u += 4) {
                float4 f = *(const float4*)&vsrc[u];
                Vt[(c0 + u + 0) * 72 + t] = f2bf(f.x);
                Vt[(c0 + u + 1) * 72 + t] = f2bf(f.y);
                Vt[(c0 + u + 2) * 72 + t] = f2bf(f.z);
                Vt[(c0 + u + 3) * 72 + t] = f2bf(f.w);
            }
        }
        __syncthreads();

        // ---- S = Q K^T (contract over d: 2 k-steps of 32) ----
        f32x4 s[4] = {};
#pragma unroll
        for (int ks = 0; ks < 2; ++ks) {
            s16x8 afr = *(const s16x8*)&Qs[(w * 16 + l16) * 72 + ks * 32 + quad * 8];
#pragma unroll
            for (int nt = 0; nt < 4; ++nt) {
                s16x8 bfr = *(const s16x8*)&Ks[(nt * 16 + l16) * 72 + ks * 32 + quad * 8];
                s[nt] = __builtin_amdgcn_mfma_f32_16x16x32_bf16(afr, bfr, s[nt], 0, 0, 0);
            }
        }

        // ---- scale + causal mask ----
        if (kt == qt) {
#pragma unroll
            for (int nt = 0; nt < 4; ++nt) {
                int col = kt * 64 + nt * 16 + l16;
#pragma unroll
                for (int r = 0; r < 4; ++r) {
                    int row = q0 + w * 16 + quad * 4 + r;
                    s[nt][r] = (col > row) ? -3.0e38f : s[nt][r] * 0.125f;
                }
            }
        } else {
#pragma unroll
            for (int nt = 0; nt < 4; ++nt)
#pragma unroll
                for (int r = 0; r < 4; ++r)
                    s[nt][r] *= 0.125f;
        }

        // ---- online softmax (per row = quad*4+r) ----
#pragma unroll
        for (int r = 0; r < 4; ++r) {
            float mx = fmaxf(fmaxf(s[0][r], s[1][r]), fmaxf(s[2][r], s[3][r]));
            mx = fmaxf(mx, __shfl_xor(mx, 1));
            mx = fmaxf(mx, __shfl_xor(mx, 2));
            mx = fmaxf(mx, __shfl_xor(mx, 4));
            mx = fmaxf(mx, __shfl_xor(mx, 8));
            float mnew = fmaxf(m_i[r], mx);
            float sc = __expf(m_i[r] - mnew);
            m_i[r] = mnew;
            float rs = 0.f;
            unsigned short pb[4];
#pragma unroll
            for (int nt = 0; nt < 4; ++nt) {
                float p = __expf(s[nt][r] - mnew);
                rs += p;
                pb[nt] = f2bf(p);
            }
            rs += __shfl_xor(rs, 1);
            rs += __shfl_xor(rs, 2);
            rs += __shfl_xor(rs, 4);
            rs += __shfl_xor(rs, 8);
            l_i[r] = l_i[r] * sc + rs;
#pragma unroll
            for (int nt = 0; nt < 4; ++nt) {
                O[nt][r] *= sc;
                Ps[w][(quad * 4 + r) * 72 + nt * 16 + l16] = pb[nt];
            }
        }

        // ---- O += P V (contract over t: 2 k-steps of 32) ----
#pragma unroll
        for (int ks = 0; ks < 2; ++ks) {
            s16x8 afr = *(const s16x8*)&Ps[w][l16 * 72 + ks * 32 + quad * 8];
#pragma unroll
            for (int nt = 0; nt < 4; ++nt) {
                s16x8 bfr = *(const s16x8*)&Vt[(nt * 16 + l16) * 72 + ks * 32 + quad * 8];
                O[nt] = __builtin_amdgcn_mfma_f32_16x16x32_bf16(afr, bfr, O[nt], 0, 0, 0);
            }
        }
    }

    // ---- normalize + store ----
#pragma unroll
    for (int r = 0; r < 4; ++r) {
        float inv = 1.f / l_i[r];
        int row = q0 + w * 16 + quad * 4 + r;
        size_t addr = ((size_t)(b * T_ + row)) * C_ + h * D_;
#pragma unroll
        for (int nt = 0; nt < 4; ++nt)
            mean[addr + nt * 16 + l16] = O[nt][r] * inv;
    }
}

// ---------------------------------------------------------------------------
// In-place inverse transform: y = exp((zmax + log(mean))/p) - 5
// ---------------------------------------------------------------------------
__global__ __launch_bounds__(256)
void y_kernel(float* __restrict__ mean, const float* __restrict__ p_param,
              const float* __restrict__ zmax) {
    int idx = blockIdx.x * 256 + threadIdx.x;
    int c = idx & (C_ - 1);
    int bt = idx >> 10;
    int b = bt >> 11;
    float p = clamp_p(p_param[c]);
    float mval = mean[idx];
    float y = expf((zmax[b * C_ + c] + logf(mval)) / p) - SHIFT_;
    mean[idx] = y;
}

// ---------------------------------------------------------------------------
extern "C" void kernel_launch(void* const* d_in, const int* in_sizes, int n_in,
                              void* d_out, int out_size, void* d_ws, size_t ws_size,
                              hipStream_t stream) {
    const float* x      = (const float*)d_in[0];
    const float* w_attn = (const float*)d_in[1];
    const float* b_attn = (const float*)d_in[2];
    const float* w_proj = (const float*)d_in[3];
    const float* b_proj = (const float*)d_in[4];
    const float* p_par  = (const float*)d_in[5];
    float* out = (float*)d_out;

    char* ws = (char*)d_ws;
    float* qkv  = (float*)ws;                                           // B*T*3C
    float* mean = (float*)(ws + (size_t)B_ * T_ * 3 * C_ * sizeof(float));
    float* zmax = (float*)(ws + (size_t)B_ * T_ * 3 * C_ * sizeof(float)
                              + (size_t)B_ * T_ * C_ * sizeof(float));  // B*C

    // 1) qkv = x @ w_attn + b_attn   [4096 x 3072]
    dim3 g1(3 * C_ / 128, (B_ * T_) / 128);
    gemm_bias_128<<<g1, 256, 0, stream>>>(x, w_attn, b_attn, qkv,
                                          B_ * T_, 3 * C_, C_);
    // 2) z_max over T per (b,c)
    zmax_kernel<<<B_ * (C_ / 64), 256, 0, stream>>>(qkv, p_par, zmax);
    // 3) v <- exp(z - zmax) in-place
    vexp_kernel<<<B_ * T_ * C_ / 256, 256, 0, stream>>>(qkv, p_par, zmax);
    // 4) MFMA flash attention -> mean
    attn_mfma<<<B_ * H_ * (T_ / 64), 256, 0, stream>>>(qkv, mean);
    // 5) y = exp((zmax + log mean)/p) - 5, in-place
    y_kernel<<<B_ * T_ * C_ / 256, 256, 0, stream>>>(mean, p_par, zmax);
    // 6) out = y @ w_proj + b_proj   [4096 x 1024]
    dim3 g2(C_ / 128, (B_ * T_) / 128);
    gemm_bias_128<<<g2, 256, 0, stream>>>(mean, w_proj, b_proj, out,
                                          B_ * T_, C_, C_);
}

// Round 4
// 493.205 us; speedup vs baseline: 7.3354x; 1.6504x over previous
//
#include <hip/hip_runtime.h>
#include <hip/hip_bf16.h>
#include <math.h>

// Problem constants (fixed by setup_inputs)
constexpr int B_ = 2;
constexpr int T_ = 2048;
constexpr int C_ = 1024;
constexpr int H_ = 16;
constexpr int D_ = 64;       // head dim
constexpr int M_ = B_ * T_;  // 4096 rows
constexpr float SHIFT_ = 5.0f;
constexpr float P_MIN_ = 1e-4f;
constexpr float P_MAX_ = 1e3f;
constexpr float V_MIN_ = 1e-10f;

typedef __attribute__((ext_vector_type(8))) short s16x8;
typedef __attribute__((ext_vector_type(4))) float f32x4;
typedef unsigned short ushort_t;

__device__ __forceinline__ float clamp_p(float pp) {
    float s = (pp >= 0.f) ? 1.f : -1.f;
    return s * fminf(fmaxf(fabsf(pp), P_MIN_), P_MAX_);
}

// round-to-nearest-even fp32 -> bf16 bits, and back
__device__ __forceinline__ unsigned short f2bf(float f) {
    unsigned int u = __float_as_uint(f);
    u += 0x7fffu + ((u >> 16) & 1u);
    return (unsigned short)(u >> 16);
}
__device__ __forceinline__ float bf2f(unsigned short h) {
    return __uint_as_float(((unsigned int)h) << 16);
}

// ---------------------------------------------------------------------------
// Split fp32 -> (hi, lo) bf16 planes. n4 = element count / 4.
// ---------------------------------------------------------------------------
__global__ __launch_bounds__(256)
void conv_hilo(const float* __restrict__ src, ushort_t* __restrict__ hi,
               ushort_t* __restrict__ lo) {
    int idx = blockIdx.x * 256 + threadIdx.x;
    float4 f = ((const float4*)src)[idx];
    ushort4 h, l;
    h.x = f2bf(f.x); l.x = f2bf(f.x - bf2f(h.x));
    h.y = f2bf(f.y); l.y = f2bf(f.y - bf2f(h.y));
    h.z = f2bf(f.z); l.z = f2bf(f.z - bf2f(h.z));
    h.w = f2bf(f.w); l.w = f2bf(f.w - bf2f(h.w));
    ((ushort4*)hi)[idx] = h;
    ((ushort4*)lo)[idx] = l;
}

// ---------------------------------------------------------------------------
// Transpose + split: W[K][N] fp32 -> Wt_hi/Wt_lo [N][K] bf16.
// 64x64 tiles via padded LDS. grid = (N/64, K/64).
// ---------------------------------------------------------------------------
__global__ __launch_bounds__(256)
void convT_hilo(const float* __restrict__ W, ushort_t* __restrict__ Wth,
                ushort_t* __restrict__ Wtl, int N, int K) {
    __shared__ float tile[64][65];
    const int k0 = blockIdx.y * 64, n0 = blockIdx.x * 64;
    const int tr = threadIdx.x >> 4;           // 0..15
    const int tc4 = (threadIdx.x & 15) * 4;    // 0..60
#pragma unroll
    for (int i = 0; i < 4; ++i) {
        float4 f = *(const float4*)&W[(size_t)(k0 + tr + i * 16) * N + n0 + tc4];
        tile[tr + i * 16][tc4 + 0] = f.x;
        tile[tr + i * 16][tc4 + 1] = f.y;
        tile[tr + i * 16][tc4 + 2] = f.z;
        tile[tr + i * 16][tc4 + 3] = f.w;
    }
    __syncthreads();
#pragma unroll
    for (int i = 0; i < 4; ++i) {
        int n = tr + i * 16;
        ushort4 h, l;
        float a0 = tile[tc4 + 0][n]; h.x = f2bf(a0); l.x = f2bf(a0 - bf2f(h.x));
        float a1 = tile[tc4 + 1][n]; h.y = f2bf(a1); l.y = f2bf(a1 - bf2f(h.y));
        float a2 = tile[tc4 + 2][n]; h.z = f2bf(a2); l.z = f2bf(a2 - bf2f(h.z));
        float a3 = tile[tc4 + 3][n]; h.w = f2bf(a3); l.w = f2bf(a3 - bf2f(h.w));
        *(ushort4*)&Wth[(size_t)(n0 + n) * K + k0 + tc4] = h;
        *(ushort4*)&Wtl[(size_t)(n0 + n) * K + k0 + tc4] = l;
    }
}

// ---------------------------------------------------------------------------
// bf16x3 MFMA GEMM: C[M,N] = A*B + bias, A=[M][K] hi/lo, B=[N][K] hi/lo (pre-T).
// acc = Ah*Bh + Al*Bh + Ah*Bl  (lo*lo dropped, ~2^-16 relative).
// 128x128x32 tile, 256 threads = 4 waves (2x2 of 64x64), 16x16x32 MFMA.
// Wave w stages LDS buffer w (pure bf16 16B copies). LDS = 32 KB.
// ---------------------------------------------------------------------------
__global__ __launch_bounds__(256)
void gemm3(const ushort_t* __restrict__ Ah, const ushort_t* __restrict__ Al,
           const ushort_t* __restrict__ Bh, const ushort_t* __restrict__ Bl,
           const float* __restrict__ bias, float* __restrict__ Cm,
           int M, int N, int K) {
    __shared__ ushort_t Ash[128 * 32];
    __shared__ ushort_t Asl[128 * 32];
    __shared__ ushort_t Bsh[128 * 32];
    __shared__ ushort_t Bsl[128 * 32];

    const int tid = threadIdx.x;
    const int w = tid >> 6;
    const int lane = tid & 63;
    const int l16 = lane & 15;
    const int quad = lane >> 4;
    const int row0 = blockIdx.y * 128, col0 = blockIdx.x * 128;
    const int wr = w >> 1, wc = w & 1;

    const ushort_t* gsrc = (w == 0) ? Ah : (w == 1) ? Al : (w == 2) ? Bh : Bl;
    ushort_t* lbuf = (w == 0) ? Ash : (w == 1) ? Asl : (w == 2) ? Bsh : Bsl;
    const int tbase = (w < 2) ? row0 : col0;
    const int srow = lane >> 2;            // 0..15
    const int scol = (lane & 3) * 8;       // 0,8,16,24

    f32x4 acc[4][4] = {};

    for (int k0 = 0; k0 < K; k0 += 32) {
        __syncthreads();
#pragma unroll
        for (int i = 0; i < 8; ++i) {
            int row = i * 16 + srow;
            s16x8 d = *(const s16x8*)&gsrc[(size_t)(tbase + row) * K + k0 + scol];
            *(s16x8*)&lbuf[row * 32 + scol] = d;
        }
        __syncthreads();

        s16x8 af[4], alf[4], bf[4], blf[4];
#pragma unroll
        for (int mi = 0; mi < 4; ++mi) {
            af[mi]  = *(const s16x8*)&Ash[(wr * 64 + mi * 16 + l16) * 32 + quad * 8];
            alf[mi] = *(const s16x8*)&Asl[(wr * 64 + mi * 16 + l16) * 32 + quad * 8];
        }
#pragma unroll
        for (int ni = 0; ni < 4; ++ni) {
            bf[ni]  = *(const s16x8*)&Bsh[(wc * 64 + ni * 16 + l16) * 32 + quad * 8];
            blf[ni] = *(const s16x8*)&Bsl[(wc * 64 + ni * 16 + l16) * 32 + quad * 8];
        }
#pragma unroll
        for (int mi = 0; mi < 4; ++mi)
#pragma unroll
            for (int ni = 0; ni < 4; ++ni) {
                acc[mi][ni] = __builtin_amdgcn_mfma_f32_16x16x32_bf16(af[mi],  bf[ni],  acc[mi][ni], 0, 0, 0);
                acc[mi][ni] = __builtin_amdgcn_mfma_f32_16x16x32_bf16(alf[mi], bf[ni],  acc[mi][ni], 0, 0, 0);
                acc[mi][ni] = __builtin_amdgcn_mfma_f32_16x16x32_bf16(af[mi],  blf[ni], acc[mi][ni], 0, 0, 0);
            }
    }

#pragma unroll
    for (int mi = 0; mi < 4; ++mi) {
#pragma unroll
        for (int r = 0; r < 4; ++r) {
            int row = row0 + wr * 64 + mi * 16 + quad * 4 + r;
#pragma unroll
            for (int ni = 0; ni < 4; ++ni) {
                int col = col0 + wc * 64 + ni * 16 + l16;
                Cm[(size_t)row * N + col] = acc[mi][ni][r] + bias[col];
            }
        }
    }
}

// ---------------------------------------------------------------------------
// z_max[b,c] = max_t p_c * log(clip(|v[b,t,c]+5|, 1e-10))
// ---------------------------------------------------------------------------
__global__ __launch_bounds__(256)
void zmax_kernel(const float* __restrict__ qkv, const float* __restrict__ p_param,
                 float* __restrict__ zmax) {
    const int ctile = blockIdx.x & (C_ / 64 - 1);
    const int b = blockIdx.x >> 4;
    const int col = threadIdx.x & 63;
    const int r = threadIdx.x >> 6;
    const int c = ctile * 64 + col;

    const float p = clamp_p(p_param[c]);
    const float* vp = qkv + (size_t)b * T_ * 3 * C_ + 2 * C_ + c;

    float lm = -INFINITY;
    for (int t = r; t < T_; t += 4) {
        float v = vp[(size_t)t * 3 * C_];
        float z = p * logf(fmaxf(fabsf(v + SHIFT_), V_MIN_));
        lm = fmaxf(lm, z);
    }
    __shared__ float red[4][64];
    red[r][col] = lm;
    __syncthreads();
    if (threadIdx.x < 64) {
        float m = fmaxf(fmaxf(red[0][threadIdx.x], red[1][threadIdx.x]),
                        fmaxf(red[2][threadIdx.x], red[3][threadIdx.x]));
        zmax[b * C_ + threadIdx.x + ctile * 64] = m;
    }
}

// ---------------------------------------------------------------------------
// In-place: v[b,t,c] <- exp(p_c*log(clip(|v+5|)) - zmax[b,c])
// ---------------------------------------------------------------------------
__global__ __launch_bounds__(256)
void vexp_kernel(float* __restrict__ qkv, const float* __restrict__ p_param,
                 const float* __restrict__ zmax) {
    int idx = blockIdx.x * 256 + threadIdx.x;
    int c = idx & (C_ - 1);
    int bt = idx >> 10;
    int b = bt >> 11;
    float p = clamp_p(p_param[c]);
    size_t addr = (size_t)bt * 3 * C_ + 2 * C_ + c;
    float v = qkv[addr];
    float z = p * logf(fmaxf(fabsf(v + SHIFT_), V_MIN_));
    qkv[addr] = expf(z - zmax[b * C_ + c]);
}

// ---------------------------------------------------------------------------
// Flash attention, bf16 MFMA (16x16x32), fp32 accumulate.
// Epilogue fused: y = exp((zmax+log(mean))/p) - 5, split to hi/lo bf16 planes
// (feeds GEMM2 directly; removes y_kernel + fp32 mean buffer).
// ---------------------------------------------------------------------------
__global__ __launch_bounds__(256)
void attn_mfma(const float* __restrict__ qkv, const float* __restrict__ p_param,
               const float* __restrict__ zmax,
               ushort_t* __restrict__ yh, ushort_t* __restrict__ yl) {
    __shared__ unsigned short Qs[64 * 72];
    __shared__ unsigned short Ks[64 * 72];
    __shared__ unsigned short Vt[64 * 72];   // Vt[d][t]
    __shared__ unsigned short Ps[4][16 * 72];

    const int tid = threadIdx.x;
    const int w = tid >> 6;
    const int lane = tid & 63;
    const int l16 = lane & 15;
    const int quad = lane >> 4;

    const int bh = blockIdx.x >> 5;
    const int qt = 31 - (blockIdx.x & 31);   // heavy tiles first
    const int b = bh >> 4;
    const int h = bh & 15;
    const int q0 = qt * 64;

    const size_t base = (size_t)b * T_ * 3 * C_;
    const float* qbase = qkv + base + (size_t)q0 * 3 * C_ + h * D_;
    const float* kbase = qkv + base + C_ + h * D_;
    const float* vbase = qkv + base + 2 * C_ + h * D_;

    {
        const int t = tid >> 2, c0 = (tid & 3) * 16;
        const float* src = qbase + (size_t)t * (3 * C_) + c0;
        unsigned short tmp[16];
#pragma unroll
        for (int u = 0; u < 16; u += 4) {
            float4 f = *(const float4*)&src[u];
            tmp[u + 0] = f2bf(f.x); tmp[u + 1] = f2bf(f.y);
            tmp[u + 2] = f2bf(f.z); tmp[u + 3] = f2bf(f.w);
        }
        *(s16x8*)&Qs[t * 72 + c0]     = *(s16x8*)&tmp[0];
        *(s16x8*)&Qs[t * 72 + c0 + 8] = *(s16x8*)&tmp[8];
    }

    f32x4 O[4] = {};
    float m_i[4], l_i[4];
#pragma unroll
    for (int r = 0; r < 4; ++r) { m_i[r] = -INFINITY; l_i[r] = 0.f; }

    for (int kt = 0; kt <= qt; ++kt) {
        __syncthreads();
        {
            const int t = tid >> 2, c0 = (tid & 3) * 16;
            const float* ksrc = kbase + (size_t)(kt * 64 + t) * (3 * C_) + c0;
            const float* vsrc = vbase + (size_t)(kt * 64 + t) * (3 * C_) + c0;
            unsigned short tk[16];
#pragma unroll
            for (int u = 0; u < 16; u += 4) {
                float4 f = *(const float4*)&ksrc[u];
                tk[u + 0] = f2bf(f.x); tk[u + 1] = f2bf(f.y);
                tk[u + 2] = f2bf(f.z); tk[u + 3] = f2bf(f.w);
            }
            *(s16x8*)&Ks[t * 72 + c0]     = *(s16x8*)&tk[0];
            *(s16x8*)&Ks[t * 72 + c0 + 8] = *(s16x8*)&tk[8];
#pragma unroll
            for (int u = 0; u < 16; u += 4) {
                float4 f = *(const float4*)&vsrc[u];
                Vt[(c0 + u + 0) * 72 + t] = f2bf(f.x);
                Vt[(c0 + u + 1) * 72 + t] = f2bf(f.y);
                Vt[(c0 + u + 2) * 72 + t] = f2bf(f.z);
                Vt[(c0 + u + 3) * 72 + t] = f2bf(f.w);
            }
        }
        __syncthreads();

        // ---- S = Q K^T ----
        f32x4 s[4] = {};
#pragma unroll
        for (int ks = 0; ks < 2; ++ks) {
            s16x8 afr = *(const s16x8*)&Qs[(w * 16 + l16) * 72 + ks * 32 + quad * 8];
#pragma unroll
            for (int nt = 0; nt < 4; ++nt) {
                s16x8 bfr = *(const s16x8*)&Ks[(nt * 16 + l16) * 72 + ks * 32 + quad * 8];
                s[nt] = __builtin_amdgcn_mfma_f32_16x16x32_bf16(afr, bfr, s[nt], 0, 0, 0);
            }
        }

        // ---- scale + causal mask ----
        if (kt == qt) {
#pragma unroll
            for (int nt = 0; nt < 4; ++nt) {
                int col = kt * 64 + nt * 16 + l16;
#pragma unroll
                for (int r = 0; r < 4; ++r) {
                    int row = q0 + w * 16 + quad * 4 + r;
                    s[nt][r] = (col > row) ? -3.0e38f : s[nt][r] * 0.125f;
                }
            }
        } else {
#pragma unroll
            for (int nt = 0; nt < 4; ++nt)
#pragma unroll
                for (int r = 0; r < 4; ++r)
                    s[nt][r] *= 0.125f;
        }

        // ---- online softmax ----
#pragma unroll
        for (int r = 0; r < 4; ++r) {
            float mx = fmaxf(fmaxf(s[0][r], s[1][r]), fmaxf(s[2][r], s[3][r]));
            mx = fmaxf(mx, __shfl_xor(mx, 1));
            mx = fmaxf(mx, __shfl_xor(mx, 2));
            mx = fmaxf(mx, __shfl_xor(mx, 4));
            mx = fmaxf(mx, __shfl_xor(mx, 8));
            float mnew = fmaxf(m_i[r], mx);
            float sc = __expf(m_i[r] - mnew);
            m_i[r] = mnew;
            float rs = 0.f;
            unsigned short pb[4];
#pragma unroll
            for (int nt = 0; nt < 4; ++nt) {
                float p = __expf(s[nt][r] - mnew);
                rs += p;
                pb[nt] = f2bf(p);
            }
            rs += __shfl_xor(rs, 1);
            rs += __shfl_xor(rs, 2);
            rs += __shfl_xor(rs, 4);
            rs += __shfl_xor(rs, 8);
            l_i[r] = l_i[r] * sc + rs;
#pragma unroll
            for (int nt = 0; nt < 4; ++nt) {
                O[nt][r] *= sc;
                Ps[w][(quad * 4 + r) * 72 + nt * 16 + l16] = pb[nt];
            }
        }

        // ---- O += P V ----
#pragma unroll
        for (int ks = 0; ks < 2; ++ks) {
            s16x8 afr = *(const s16x8*)&Ps[w][l16 * 72 + ks * 32 + quad * 8];
#pragma unroll
            for (int nt = 0; nt < 4; ++nt) {
                s16x8 bfr = *(const s16x8*)&Vt[(nt * 16 + l16) * 72 + ks * 32 + quad * 8];
                O[nt] = __builtin_amdgcn_mfma_f32_16x16x32_bf16(afr, bfr, O[nt], 0, 0, 0);
            }
        }
    }

    // ---- fused epilogue: normalize, inverse power transform, hi/lo split ----
#pragma unroll
    for (int r = 0; r < 4; ++r) {
        float inv = 1.f / l_i[r];
        int row = q0 + w * 16 + quad * 4 + r;
#pragma unroll
        for (int nt = 0; nt < 4; ++nt) {
            int c = h * D_ + nt * 16 + l16;
            float mval = O[nt][r] * inv;
            float p = clamp_p(p_param[c]);
            float yv = expf((zmax[b * C_ + c] + logf(mval)) / p) - SHIFT_;
            unsigned short hh = f2bf(yv);
            size_t a = (size_t)(b * T_ + row) * C_ + c;
            yh[a] = hh;
            yl[a] = f2bf(yv - bf2f(hh));
        }
    }
}

// ---------------------------------------------------------------------------
extern "C" void kernel_launch(void* const* d_in, const int* in_sizes, int n_in,
                              void* d_out, int out_size, void* d_ws, size_t ws_size,
                              hipStream_t stream) {
    const float* x      = (const float*)d_in[0];
    const float* w_attn = (const float*)d_in[1];
    const float* b_attn = (const float*)d_in[2];
    const float* w_proj = (const float*)d_in[3];
    const float* b_proj = (const float*)d_in[4];
    const float* p_par  = (const float*)d_in[5];
    float* out = (float*)d_out;

    char* ws = (char*)d_ws;
    float* qkv = (float*)ws;                                  // M x 3C fp32 (50.3 MB)
    char* p1 = ws + (size_t)M_ * 3 * C_ * sizeof(float);
    ushort_t* xh = (ushort_t*)p1;                             // M x C bf16 (aliases yh)
    ushort_t* xl = xh + (size_t)M_ * C_;                      // (aliases yl)
    ushort_t* wth = xl + (size_t)M_ * C_;                     // 3C x C bf16 (aliases wpt)
    ushort_t* wtl = wth + (size_t)3 * C_ * C_;
    float* zmax = (float*)(wtl + (size_t)3 * C_ * C_);        // B x C

    // 1) split x -> hi/lo bf16
    conv_hilo<<<M_ * C_ / 1024, 256, 0, stream>>>(x, xh, xl);
    // 2) transpose+split w_attn -> [3C][C]
    convT_hilo<<<dim3(3 * C_ / 64, C_ / 64), 256, 0, stream>>>(w_attn, wth, wtl, 3 * C_, C_);
    // 3) qkv = x @ w_attn + b_attn  (bf16x3 MFMA)
    gemm3<<<dim3(3 * C_ / 128, M_ / 128), 256, 0, stream>>>(xh, xl, wth, wtl,
                                                            b_attn, qkv, M_, 3 * C_, C_);
    // 4) z_max over T per (b,c)
    zmax_kernel<<<B_ * (C_ / 64), 256, 0, stream>>>(qkv, p_par, zmax);
    // 5) v <- exp(z - zmax) in-place
    vexp_kernel<<<B_ * T_ * C_ / 256, 256, 0, stream>>>(qkv, p_par, zmax);
    // 6) MFMA flash attention + fused y transform -> yh/yl (alias xh/xl)
    attn_mfma<<<B_ * H_ * (T_ / 64), 256, 0, stream>>>(qkv, p_par, zmax, xh, xl);
    // 7) transpose+split w_proj -> [C][C] (reuses wt buffers)
    convT_hilo<<<dim3(C_ / 64, C_ / 64), 256, 0, stream>>>(w_proj, wth, wtl, C_, C_);
    // 8) out = y @ w_proj + b_proj  (bf16x3 MFMA)
    gemm3<<<dim3(C_ / 128, M_ / 128), 256, 0, stream>>>(xh, xl, wth, wtl,
                                                        b_proj, out, M_, C_, C_);
}

// Round 5
// 461.235 us; speedup vs baseline: 7.8439x; 1.0693x over previous
//
#include <hip/hip_runtime.h>
#include <hip/hip_bf16.h>
#include <math.h>

// Problem constants (fixed by setup_inputs)
constexpr int B_ = 2;
constexpr int T_ = 2048;
constexpr int C_ = 1024;
constexpr int H_ = 16;
constexpr int D_ = 64;       // head dim
constexpr int M_ = B_ * T_;  // 4096 rows
constexpr float SHIFT_ = 5.0f;
constexpr float P_MIN_ = 1e-4f;
constexpr float P_MAX_ = 1e3f;
constexpr float V_MIN_ = 1e-10f;

typedef __attribute__((ext_vector_type(8))) short s16x8;
typedef __attribute__((ext_vector_type(4))) float f32x4;
typedef unsigned short ushort_t;

__device__ __forceinline__ float clamp_p(float pp) {
    float s = (pp >= 0.f) ? 1.f : -1.f;
    return s * fminf(fmaxf(fabsf(pp), P_MIN_), P_MAX_);
}

// round-to-nearest-even fp32 -> bf16 bits, and back
__device__ __forceinline__ unsigned short f2bf(float f) {
    unsigned int u = __float_as_uint(f);
    u += 0x7fffu + ((u >> 16) & 1u);
    return (unsigned short)(u >> 16);
}
__device__ __forceinline__ float bf2f(unsigned short h) {
    return __uint_as_float(((unsigned int)h) << 16);
}

// ---------------------------------------------------------------------------
// Split fp32 -> (hi, lo) bf16 planes.
// ---------------------------------------------------------------------------
__global__ __launch_bounds__(256)
void conv_hilo(const float* __restrict__ src, ushort_t* __restrict__ hi,
               ushort_t* __restrict__ lo) {
    int idx = blockIdx.x * 256 + threadIdx.x;
    float4 f = ((const float4*)src)[idx];
    ushort4 h, l;
    h.x = f2bf(f.x); l.x = f2bf(f.x - bf2f(h.x));
    h.y = f2bf(f.y); l.y = f2bf(f.y - bf2f(h.y));
    h.z = f2bf(f.z); l.z = f2bf(f.z - bf2f(h.z));
    h.w = f2bf(f.w); l.w = f2bf(f.w - bf2f(h.w));
    ((ushort4*)hi)[idx] = h;
    ((ushort4*)lo)[idx] = l;
}

// ---------------------------------------------------------------------------
// Transpose + split: W[K][N] fp32 -> Wt_hi/Wt_lo [N][K] bf16.
// ---------------------------------------------------------------------------
__global__ __launch_bounds__(256)
void convT_hilo(const float* __restrict__ W, ushort_t* __restrict__ Wth,
                ushort_t* __restrict__ Wtl, int N, int K) {
    __shared__ float tile[64][65];
    const int k0 = blockIdx.y * 64, n0 = blockIdx.x * 64;
    const int tr = threadIdx.x >> 4;
    const int tc4 = (threadIdx.x & 15) * 4;
#pragma unroll
    for (int i = 0; i < 4; ++i) {
        float4 f = *(const float4*)&W[(size_t)(k0 + tr + i * 16) * N + n0 + tc4];
        tile[tr + i * 16][tc4 + 0] = f.x;
        tile[tr + i * 16][tc4 + 1] = f.y;
        tile[tr + i * 16][tc4 + 2] = f.z;
        tile[tr + i * 16][tc4 + 3] = f.w;
    }
    __syncthreads();
#pragma unroll
    for (int i = 0; i < 4; ++i) {
        int n = tr + i * 16;
        ushort4 h, l;
        float a0 = tile[tc4 + 0][n]; h.x = f2bf(a0); l.x = f2bf(a0 - bf2f(h.x));
        float a1 = tile[tc4 + 1][n]; h.y = f2bf(a1); l.y = f2bf(a1 - bf2f(h.y));
        float a2 = tile[tc4 + 2][n]; h.z = f2bf(a2); l.z = f2bf(a2 - bf2f(h.z));
        float a3 = tile[tc4 + 3][n]; h.w = f2bf(a3); l.w = f2bf(a3 - bf2f(h.w));
        *(ushort4*)&Wth[(size_t)(n0 + n) * K + k0 + tc4] = h;
        *(ushort4*)&Wtl[(size_t)(n0 + n) * K + k0 + tc4] = l;
    }
}

// ---------------------------------------------------------------------------
// bf16x3 MFMA GEMM (unchanged from R4).
// ---------------------------------------------------------------------------
__global__ __launch_bounds__(256)
void gemm3(const ushort_t* __restrict__ Ah, const ushort_t* __restrict__ Al,
           const ushort_t* __restrict__ Bh, const ushort_t* __restrict__ Bl,
           const float* __restrict__ bias, float* __restrict__ Cm,
           int M, int N, int K) {
    __shared__ ushort_t Ash[128 * 32];
    __shared__ ushort_t Asl[128 * 32];
    __shared__ ushort_t Bsh[128 * 32];
    __shared__ ushort_t Bsl[128 * 32];

    const int tid = threadIdx.x;
    const int w = tid >> 6;
    const int lane = tid & 63;
    const int l16 = lane & 15;
    const int quad = lane >> 4;
    const int row0 = blockIdx.y * 128, col0 = blockIdx.x * 128;
    const int wr = w >> 1, wc = w & 1;

    const ushort_t* gsrc = (w == 0) ? Ah : (w == 1) ? Al : (w == 2) ? Bh : Bl;
    ushort_t* lbuf = (w == 0) ? Ash : (w == 1) ? Asl : (w == 2) ? Bsh : Bsl;
    const int tbase = (w < 2) ? row0 : col0;
    const int srow = lane >> 2;
    const int scol = (lane & 3) * 8;

    f32x4 acc[4][4] = {};

    for (int k0 = 0; k0 < K; k0 += 32) {
        __syncthreads();
#pragma unroll
        for (int i = 0; i < 8; ++i) {
            int row = i * 16 + srow;
            s16x8 d = *(const s16x8*)&gsrc[(size_t)(tbase + row) * K + k0 + scol];
            *(s16x8*)&lbuf[row * 32 + scol] = d;
        }
        __syncthreads();

        s16x8 af[4], alf[4], bf[4], blf[4];
#pragma unroll
        for (int mi = 0; mi < 4; ++mi) {
            af[mi]  = *(const s16x8*)&Ash[(wr * 64 + mi * 16 + l16) * 32 + quad * 8];
            alf[mi] = *(const s16x8*)&Asl[(wr * 64 + mi * 16 + l16) * 32 + quad * 8];
        }
#pragma unroll
        for (int ni = 0; ni < 4; ++ni) {
            bf[ni]  = *(const s16x8*)&Bsh[(wc * 64 + ni * 16 + l16) * 32 + quad * 8];
            blf[ni] = *(const s16x8*)&Bsl[(wc * 64 + ni * 16 + l16) * 32 + quad * 8];
        }
#pragma unroll
        for (int mi = 0; mi < 4; ++mi)
#pragma unroll
            for (int ni = 0; ni < 4; ++ni) {
                acc[mi][ni] = __builtin_amdgcn_mfma_f32_16x16x32_bf16(af[mi],  bf[ni],  acc[mi][ni], 0, 0, 0);
                acc[mi][ni] = __builtin_amdgcn_mfma_f32_16x16x32_bf16(alf[mi], bf[ni],  acc[mi][ni], 0, 0, 0);
                acc[mi][ni] = __builtin_amdgcn_mfma_f32_16x16x32_bf16(af[mi],  blf[ni], acc[mi][ni], 0, 0, 0);
            }
    }

#pragma unroll
    for (int mi = 0; mi < 4; ++mi) {
#pragma unroll
        for (int r = 0; r < 4; ++r) {
            int row = row0 + wr * 64 + mi * 16 + quad * 4 + r;
#pragma unroll
            for (int ni = 0; ni < 4; ++ni) {
                int col = col0 + wc * 64 + ni * 16 + l16;
                Cm[(size_t)row * N + col] = acc[mi][ni][r] + bias[col];
            }
        }
    }
}

// ---------------------------------------------------------------------------
// z_max[b,c] = max_t p_c * log(clip(|v[b,t,c]+5|, 1e-10))
// ---------------------------------------------------------------------------
__global__ __launch_bounds__(256)
void zmax_kernel(const float* __restrict__ qkv, const float* __restrict__ p_param,
                 float* __restrict__ zmax) {
    const int ctile = blockIdx.x & (C_ / 64 - 1);
    const int b = blockIdx.x >> 4;
    const int col = threadIdx.x & 63;
    const int r = threadIdx.x >> 6;
    const int c = ctile * 64 + col;

    const float p = clamp_p(p_param[c]);
    const float* vp = qkv + (size_t)b * T_ * 3 * C_ + 2 * C_ + c;

    float lm = -INFINITY;
    for (int t = r; t < T_; t += 4) {
        float v = vp[(size_t)t * 3 * C_];
        float z = p * logf(fmaxf(fabsf(v + SHIFT_), V_MIN_));
        lm = fmaxf(lm, z);
    }
    __shared__ float red[4][64];
    red[r][col] = lm;
    __syncthreads();
    if (threadIdx.x < 64) {
        float m = fmaxf(fmaxf(red[0][threadIdx.x], red[1][threadIdx.x]),
                        fmaxf(red[2][threadIdx.x], red[3][threadIdx.x]));
        zmax[b * C_ + threadIdx.x + ctile * 64] = m;
    }
}

// ---------------------------------------------------------------------------
// prep_kv: one-shot K/V preparation per (b,h,t-tile).
//   kbf [b][h][t][d]       bf16, 16B-group swizzle g' = g ^ (t&7)
//   vtbf[b][h][tile][d][t] bf16 (V transposed + GeM transform), g' = g ^ (d&7)
// Tile image == desired LDS image, so attention stages with plain 16B copies.
// ---------------------------------------------------------------------------
__global__ __launch_bounds__(256)
void prep_kv(const float* __restrict__ qkv, const float* __restrict__ p_param,
             const float* __restrict__ zmax,
             ushort_t* __restrict__ kbf, ushort_t* __restrict__ vtbf) {
    __shared__ ushort_t VtL[64 * 72];

    const int blk = blockIdx.x;
    const int tt = blk & 31;
    const int bh = blk >> 5;
    const int b = bh >> 4;
    const int h = bh & 15;
    const int t0 = tt * 64;

    const int tl = threadIdx.x >> 2;          // local row 0..63
    const int c0 = (threadIdx.x & 3) * 16;    // col chunk
    const int g0 = c0 >> 3;                   // group index (0,2,4,6)

    const size_t rowbase = (size_t)b * T_ * 3 * C_ + (size_t)(t0 + tl) * 3 * C_ + h * D_;

    // ---- K: convert to bf16, swizzled ----
    {
        const float* ksrc = qkv + rowbase + C_ + c0;
        ushort_t tk[16];
#pragma unroll
        for (int u = 0; u < 16; u += 4) {
            float4 f = *(const float4*)&ksrc[u];
            tk[u + 0] = f2bf(f.x); tk[u + 1] = f2bf(f.y);
            tk[u + 2] = f2bf(f.z); tk[u + 3] = f2bf(f.w);
        }
        size_t krow = ((size_t)bh * T_ + t0 + tl) * 64;
        *(s16x8*)&kbf[krow + ((g0)     ^ (tl & 7)) * 8] = *(s16x8*)&tk[0];
        *(s16x8*)&kbf[krow + ((g0 + 1) ^ (tl & 7)) * 8] = *(s16x8*)&tk[8];
    }

    // ---- V: GeM transform, transpose via LDS, swizzled ----
    {
        const float* vsrc = qkv + rowbase + 2 * C_ + c0;
#pragma unroll
        for (int u = 0; u < 16; u += 4) {
            float4 f = *(const float4*)&vsrc[u];
            float vv[4] = {f.x, f.y, f.z, f.w};
#pragma unroll
            for (int q = 0; q < 4; ++q) {
                int c = h * D_ + c0 + u + q;
                float p = clamp_p(p_param[c]);
                float z = p * __logf(fmaxf(fabsf(vv[q] + SHIFT_), V_MIN_));
                float val = __expf(z - zmax[b * C_ + c]);
                VtL[(c0 + u + q) * 72 + tl] = f2bf(val);
            }
        }
    }
    __syncthreads();
    {
        const int d = tl;                     // output row = head dim
        s16x8 r0 = *(const s16x8*)&VtL[d * 72 + c0];
        s16x8 r1 = *(const s16x8*)&VtL[d * 72 + c0 + 8];
        size_t vbase = ((size_t)bh * 32 + tt) * 4096 + (size_t)d * 64;
        *(s16x8*)&vtbf[vbase + ((g0)     ^ (d & 7)) * 8] = r0;
        *(s16x8*)&vtbf[vbase + ((g0 + 1) ^ (d & 7)) * 8] = r1;
    }
}

// ---------------------------------------------------------------------------
// Flash attention, bf16 MFMA (16x16x32), fp32 accumulate.
// K/V staged as pure 16B bf16 copies from prep'd swizzled tiles.
// Q staged once per block (fp32 -> bf16, pre-scaled by 1/8).
// Fused epilogue: y = exp((zmax+log(mean))/p) - 5 -> hi/lo bf16 planes.
// ---------------------------------------------------------------------------
__global__ __launch_bounds__(256)
void attn_mfma(const float* __restrict__ qkv, const float* __restrict__ p_param,
               const float* __restrict__ zmax,
               const ushort_t* __restrict__ kbf, const ushort_t* __restrict__ vtbf,
               ushort_t* __restrict__ yh, ushort_t* __restrict__ yl) {
    __shared__ ushort_t Qs[64 * 64];
    __shared__ ushort_t Ks[64 * 64];
    __shared__ ushort_t Vt[64 * 64];
    __shared__ ushort_t Ps[4][16 * 72];

    const int tid = threadIdx.x;
    const int w = tid >> 6;
    const int lane = tid & 63;
    const int l16 = lane & 15;
    const int quad = lane >> 4;

    const int bh = blockIdx.x >> 5;
    const int qt = 31 - (blockIdx.x & 31);   // heavy tiles first
    const int b = bh >> 4;
    const int h = bh & 15;
    const int q0 = qt * 64;

    // stage Q tile: row r=tid>>2, 16 cols from (tid&3)*16; pre-scale by 1/8
    {
        const int r = tid >> 2, c0 = (tid & 3) * 16, g0 = c0 >> 3;
        const float* src = qkv + (size_t)b * T_ * 3 * C_
                         + (size_t)(q0 + r) * 3 * C_ + h * D_ + c0;
        ushort_t tmp[16];
#pragma unroll
        for (int u = 0; u < 16; u += 4) {
            float4 f = *(const float4*)&src[u];
            tmp[u + 0] = f2bf(f.x * 0.125f); tmp[u + 1] = f2bf(f.y * 0.125f);
            tmp[u + 2] = f2bf(f.z * 0.125f); tmp[u + 3] = f2bf(f.w * 0.125f);
        }
        *(s16x8*)&Qs[r * 64 + ((g0)     ^ (r & 7)) * 8] = *(s16x8*)&tmp[0];
        *(s16x8*)&Qs[r * 64 + ((g0 + 1) ^ (r & 7)) * 8] = *(s16x8*)&tmp[8];
    }

    // swizzled group offsets for fragment reads (k-step 0/1)
    const int sg0 = ((0 + quad) ^ (l16 & 7)) * 8;
    const int sg1 = ((4 + quad) ^ (l16 & 7)) * 8;

    f32x4 O[4] = {};
    float m_i[4], l_i[4];
#pragma unroll
    for (int r = 0; r < 4; ++r) { m_i[r] = -INFINITY; l_i[r] = 0.f; }

    const ushort_t* khead = kbf + (size_t)bh * T_ * 64;
    const ushort_t* vhead = vtbf + (size_t)bh * 32 * 4096;

    for (int kt = 0; kt <= qt; ++kt) {
        __syncthreads();
        {
            const ushort_t* ktile = khead + (size_t)kt * 4096;
            const ushort_t* vtile = vhead + (size_t)kt * 4096;
#pragma unroll
            for (int i = 0; i < 2; ++i) {
                int off = (tid + i * 256) * 8;
                *(s16x8*)&Ks[off] = *(const s16x8*)&ktile[off];
                *(s16x8*)&Vt[off] = *(const s16x8*)&vtile[off];
            }
        }
        __syncthreads();

        // ---- S = Q K^T (Q pre-scaled) ----
        f32x4 s[4] = {};
#pragma unroll
        for (int ks = 0; ks < 2; ++ks) {
            const int sg = ks ? sg1 : sg0;
            s16x8 afr = *(const s16x8*)&Qs[(w * 16 + l16) * 64 + sg];
#pragma unroll
            for (int nt = 0; nt < 4; ++nt) {
                s16x8 bfr = *(const s16x8*)&Ks[(nt * 16 + l16) * 64 + sg];
                s[nt] = __builtin_amdgcn_mfma_f32_16x16x32_bf16(afr, bfr, s[nt], 0, 0, 0);
            }
        }

        // ---- causal mask (diag tile only; scale already in Q) ----
        if (kt == qt) {
#pragma unroll
            for (int nt = 0; nt < 4; ++nt) {
                int col = nt * 16 + l16;
#pragma unroll
                for (int r = 0; r < 4; ++r) {
                    int row = w * 16 + quad * 4 + r;
                    if (col > row) s[nt][r] = -3.0e38f;
                }
            }
        }

        // ---- online softmax ----
#pragma unroll
        for (int r = 0; r < 4; ++r) {
            float mx = fmaxf(fmaxf(s[0][r], s[1][r]), fmaxf(s[2][r], s[3][r]));
            mx = fmaxf(mx, __shfl_xor(mx, 1));
            mx = fmaxf(mx, __shfl_xor(mx, 2));
            mx = fmaxf(mx, __shfl_xor(mx, 4));
            mx = fmaxf(mx, __shfl_xor(mx, 8));
            float mnew = fmaxf(m_i[r], mx);
            float sc = __expf(m_i[r] - mnew);
            m_i[r] = mnew;
            float rs = 0.f;
            unsigned short pb[4];
#pragma unroll
            for (int nt = 0; nt < 4; ++nt) {
                float p = __expf(s[nt][r] - mnew);
                rs += p;
                pb[nt] = f2bf(p);
            }
            rs += __shfl_xor(rs, 1);
            rs += __shfl_xor(rs, 2);
            rs += __shfl_xor(rs, 4);
            rs += __shfl_xor(rs, 8);
            l_i[r] = l_i[r] * sc + rs;
#pragma unroll
            for (int nt = 0; nt < 4; ++nt) {
                O[nt][r] *= sc;
                Ps[w][(quad * 4 + r) * 72 + nt * 16 + l16] = pb[nt];
            }
        }

        // ---- O += P V ----
#pragma unroll
        for (int ks = 0; ks < 2; ++ks) {
            const int sg = ks ? sg1 : sg0;
            s16x8 afr = *(const s16x8*)&Ps[w][l16 * 72 + ks * 32 + quad * 8];
#pragma unroll
            for (int nt = 0; nt < 4; ++nt) {
                s16x8 bfr = *(const s16x8*)&Vt[(nt * 16 + l16) * 64 + sg];
                O[nt] = __builtin_amdgcn_mfma_f32_16x16x32_bf16(afr, bfr, O[nt], 0, 0, 0);
            }
        }
    }

    // ---- fused epilogue: normalize, inverse power transform, hi/lo split ----
#pragma unroll
    for (int r = 0; r < 4; ++r) {
        float inv = 1.f / l_i[r];
        int row = q0 + w * 16 + quad * 4 + r;
#pragma unroll
        for (int nt = 0; nt < 4; ++nt) {
            int c = h * D_ + nt * 16 + l16;
            float mval = O[nt][r] * inv;
            float p = clamp_p(p_param[c]);
            float yv = expf((zmax[b * C_ + c] + logf(mval)) / p) - SHIFT_;
            unsigned short hh = f2bf(yv);
            size_t a = (size_t)(b * T_ + row) * C_ + c;
            yh[a] = hh;
            yl[a] = f2bf(yv - bf2f(hh));
        }
    }
}

// ---------------------------------------------------------------------------
extern "C" void kernel_launch(void* const* d_in, const int* in_sizes, int n_in,
                              void* d_out, int out_size, void* d_ws, size_t ws_size,
                              hipStream_t stream) {
    const float* x      = (const float*)d_in[0];
    const float* w_attn = (const float*)d_in[1];
    const float* b_attn = (const float*)d_in[2];
    const float* w_proj = (const float*)d_in[3];
    const float* b_proj = (const float*)d_in[4];
    const float* p_par  = (const float*)d_in[5];
    float* out = (float*)d_out;

    char* ws = (char*)d_ws;
    float* qkv = (float*)ws;                                  // M x 3C fp32
    char* p1 = ws + (size_t)M_ * 3 * C_ * sizeof(float);
    ushort_t* xh = (ushort_t*)p1;                             // M x C bf16 (aliases yh)
    ushort_t* xl = xh + (size_t)M_ * C_;                      // (aliases yl)
    ushort_t* wth = xl + (size_t)M_ * C_;                     // 3C x C bf16
    ushort_t* wtl = wth + (size_t)3 * C_ * C_;
    float* zmax = (float*)(wtl + (size_t)3 * C_ * C_);        // B x C
    ushort_t* kbf  = (ushort_t*)((char*)zmax + B_ * C_ * sizeof(float));  // BH x T x 64
    ushort_t* vtbf = kbf + (size_t)B_ * H_ * T_ * 64;                     // BH x 32 x 64 x 64

    // 1) split x -> hi/lo bf16
    conv_hilo<<<M_ * C_ / 1024, 256, 0, stream>>>(x, xh, xl);
    // 2) transpose+split w_attn -> [3C][C]
    convT_hilo<<<dim3(3 * C_ / 64, C_ / 64), 256, 0, stream>>>(w_attn, wth, wtl, 3 * C_, C_);
    // 3) qkv = x @ w_attn + b_attn  (bf16x3 MFMA)
    gemm3<<<dim3(3 * C_ / 128, M_ / 128), 256, 0, stream>>>(xh, xl, wth, wtl,
                                                            b_attn, qkv, M_, 3 * C_, C_);
    // 4) z_max over T per (b,c)
    zmax_kernel<<<B_ * (C_ / 64), 256, 0, stream>>>(qkv, p_par, zmax);
    // 5) prep K (bf16 swizzled) + V (GeM transform, transposed, swizzled)
    prep_kv<<<B_ * H_ * 32, 256, 0, stream>>>(qkv, p_par, zmax, kbf, vtbf);
    // 6) MFMA flash attention + fused y transform -> yh/yl (alias xh/xl)
    attn_mfma<<<B_ * H_ * (T_ / 64), 256, 0, stream>>>(qkv, p_par, zmax,
                                                       kbf, vtbf, xh, xl);
    // 7) transpose+split w_proj -> [C][C]
    convT_hilo<<<dim3(C_ / 64, C_ / 64), 256, 0, stream>>>(w_proj, wth, wtl, C_, C_);
    // 8) out = y @ w_proj + b_proj  (bf16x3 MFMA)
    gemm3<<<dim3(C_ / 128, M_ / 128), 256, 0, stream>>>(xh, xl, wth, wtl,
                                                        b_proj, out, M_, C_, C_);
}

// Round 6
// 452.587 us; speedup vs baseline: 7.9937x; 1.0191x over previous
//
#include <hip/hip_runtime.h>
#include <hip/hip_bf16.h>
#include <math.h>

// Problem constants (fixed by setup_inputs)
constexpr int B_ = 2;
constexpr int T_ = 2048;
constexpr int C_ = 1024;
constexpr int H_ = 16;
constexpr int D_ = 64;       // head dim
constexpr int M_ = B_ * T_;  // 4096 rows
constexpr float SHIFT_ = 5.0f;
constexpr float P_MIN_ = 1e-4f;
constexpr float P_MAX_ = 1e3f;
constexpr float V_MIN_ = 1e-10f;

typedef __attribute__((ext_vector_type(8))) short s16x8;
typedef __attribute__((ext_vector_type(4))) float f32x4;
typedef unsigned short ushort_t;

__device__ __forceinline__ float clamp_p(float pp) {
    float s = (pp >= 0.f) ? 1.f : -1.f;
    return s * fminf(fmaxf(fabsf(pp), P_MIN_), P_MAX_);
}

// round-to-nearest-even fp32 -> bf16 bits, and back
__device__ __forceinline__ unsigned short f2bf(float f) {
    unsigned int u = __float_as_uint(f);
    u += 0x7fffu + ((u >> 16) & 1u);
    return (unsigned short)(u >> 16);
}
__device__ __forceinline__ float bf2f(unsigned short h) {
    return __uint_as_float(((unsigned int)h) << 16);
}

// async global->LDS, 16B per lane. LDS dest must be (wave-uniform base + lane*16).
__device__ __forceinline__ void gload_lds16(const void* g, void* l) {
    __builtin_amdgcn_global_load_lds(
        (const __attribute__((address_space(1))) unsigned int*)g,
        (__attribute__((address_space(3))) unsigned int*)l, 16, 0, 0);
}

// ---------------------------------------------------------------------------
// Split fp32 -> (hi, lo) bf16 planes.
// ---------------------------------------------------------------------------
__global__ __launch_bounds__(256)
void conv_hilo(const float* __restrict__ src, ushort_t* __restrict__ hi,
               ushort_t* __restrict__ lo) {
    int idx = blockIdx.x * 256 + threadIdx.x;
    float4 f = ((const float4*)src)[idx];
    ushort4 h, l;
    h.x = f2bf(f.x); l.x = f2bf(f.x - bf2f(h.x));
    h.y = f2bf(f.y); l.y = f2bf(f.y - bf2f(h.y));
    h.z = f2bf(f.z); l.z = f2bf(f.z - bf2f(h.z));
    h.w = f2bf(f.w); l.w = f2bf(f.w - bf2f(h.w));
    ((ushort4*)hi)[idx] = h;
    ((ushort4*)lo)[idx] = l;
}

// ---------------------------------------------------------------------------
// Transpose + split: W[K][N] fp32 -> Wt_hi/Wt_lo [N][K] bf16.
// ---------------------------------------------------------------------------
__global__ __launch_bounds__(256)
void convT_hilo(const float* __restrict__ W, ushort_t* __restrict__ Wth,
                ushort_t* __restrict__ Wtl, int N, int K) {
    __shared__ float tile[64][65];
    const int k0 = blockIdx.y * 64, n0 = blockIdx.x * 64;
    const int tr = threadIdx.x >> 4;
    const int tc4 = (threadIdx.x & 15) * 4;
#pragma unroll
    for (int i = 0; i < 4; ++i) {
        float4 f = *(const float4*)&W[(size_t)(k0 + tr + i * 16) * N + n0 + tc4];
        tile[tr + i * 16][tc4 + 0] = f.x;
        tile[tr + i * 16][tc4 + 1] = f.y;
        tile[tr + i * 16][tc4 + 2] = f.z;
        tile[tr + i * 16][tc4 + 3] = f.w;
    }
    __syncthreads();
#pragma unroll
    for (int i = 0; i < 4; ++i) {
        int n = tr + i * 16;
        ushort4 h, l;
        float a0 = tile[tc4 + 0][n]; h.x = f2bf(a0); l.x = f2bf(a0 - bf2f(h.x));
        float a1 = tile[tc4 + 1][n]; h.y = f2bf(a1); l.y = f2bf(a1 - bf2f(h.y));
        float a2 = tile[tc4 + 2][n]; h.z = f2bf(a2); l.z = f2bf(a2 - bf2f(h.z));
        float a3 = tile[tc4 + 3][n]; h.w = f2bf(a3); l.w = f2bf(a3 - bf2f(h.w));
        *(ushort4*)&Wth[(size_t)(n0 + n) * K + k0 + tc4] = h;
        *(ushort4*)&Wtl[(size_t)(n0 + n) * K + k0 + tc4] = l;
    }
}

// ---------------------------------------------------------------------------
// bf16x3 MFMA GEMM. Staging now via global_load_lds (16B/lane async DMA):
// LDS byte offset (row*32+scol)*2 == i*1024 + lane*16 (wave-uniform + lane*16).
// ---------------------------------------------------------------------------
__global__ __launch_bounds__(256)
void gemm3(const ushort_t* __restrict__ Ah, const ushort_t* __restrict__ Al,
           const ushort_t* __restrict__ Bh, const ushort_t* __restrict__ Bl,
           const float* __restrict__ bias, float* __restrict__ Cm,
           int M, int N, int K) {
    __shared__ ushort_t Ash[128 * 32];
    __shared__ ushort_t Asl[128 * 32];
    __shared__ ushort_t Bsh[128 * 32];
    __shared__ ushort_t Bsl[128 * 32];

    const int tid = threadIdx.x;
    const int w = tid >> 6;
    const int lane = tid & 63;
    const int l16 = lane & 15;
    const int quad = lane >> 4;
    const int row0 = blockIdx.y * 128, col0 = blockIdx.x * 128;
    const int wr = w >> 1, wc = w & 1;

    const ushort_t* gsrc = (w == 0) ? Ah : (w == 1) ? Al : (w == 2) ? Bh : Bl;
    ushort_t* lbuf = (w == 0) ? Ash : (w == 1) ? Asl : (w == 2) ? Bsh : Bsl;
    const int tbase = (w < 2) ? row0 : col0;
    const int srow = lane >> 2;
    const int scol = (lane & 3) * 8;

    f32x4 acc[4][4] = {};

    for (int k0 = 0; k0 < K; k0 += 32) {
        __syncthreads();
#pragma unroll
        for (int i = 0; i < 8; ++i) {
            int row = i * 16 + srow;
            gload_lds16(&gsrc[(size_t)(tbase + row) * K + k0 + scol],
                        &lbuf[row * 32 + scol]);
        }
        __syncthreads();

        s16x8 af[4], alf[4], bf[4], blf[4];
#pragma unroll
        for (int mi = 0; mi < 4; ++mi) {
            af[mi]  = *(const s16x8*)&Ash[(wr * 64 + mi * 16 + l16) * 32 + quad * 8];
            alf[mi] = *(const s16x8*)&Asl[(wr * 64 + mi * 16 + l16) * 32 + quad * 8];
        }
#pragma unroll
        for (int ni = 0; ni < 4; ++ni) {
            bf[ni]  = *(const s16x8*)&Bsh[(wc * 64 + ni * 16 + l16) * 32 + quad * 8];
            blf[ni] = *(const s16x8*)&Bsl[(wc * 64 + ni * 16 + l16) * 32 + quad * 8];
        }
#pragma unroll
        for (int mi = 0; mi < 4; ++mi)
#pragma unroll
            for (int ni = 0; ni < 4; ++ni) {
                acc[mi][ni] = __builtin_amdgcn_mfma_f32_16x16x32_bf16(af[mi],  bf[ni],  acc[mi][ni], 0, 0, 0);
                acc[mi][ni] = __builtin_amdgcn_mfma_f32_16x16x32_bf16(alf[mi], bf[ni],  acc[mi][ni], 0, 0, 0);
                acc[mi][ni] = __builtin_amdgcn_mfma_f32_16x16x32_bf16(af[mi],  blf[ni], acc[mi][ni], 0, 0, 0);
            }
    }

#pragma unroll
    for (int mi = 0; mi < 4; ++mi) {
#pragma unroll
        for (int r = 0; r < 4; ++r) {
            int row = row0 + wr * 64 + mi * 16 + quad * 4 + r;
#pragma unroll
            for (int ni = 0; ni < 4; ++ni) {
                int col = col0 + wc * 64 + ni * 16 + l16;
                Cm[(size_t)row * N + col] = acc[mi][ni][r] + bias[col];
            }
        }
    }
}

// ---------------------------------------------------------------------------
// z_max[b,c] = max_t p_c * log(clip(|v[b,t,c]+5|, 1e-10))
// ---------------------------------------------------------------------------
__global__ __launch_bounds__(256)
void zmax_kernel(const float* __restrict__ qkv, const float* __restrict__ p_param,
                 float* __restrict__ zmax) {
    const int ctile = blockIdx.x & (C_ / 64 - 1);
    const int b = blockIdx.x >> 4;
    const int col = threadIdx.x & 63;
    const int r = threadIdx.x >> 6;
    const int c = ctile * 64 + col;

    const float p = clamp_p(p_param[c]);
    const float* vp = qkv + (size_t)b * T_ * 3 * C_ + 2 * C_ + c;

    float lm = -INFINITY;
    for (int t = r; t < T_; t += 4) {
        float v = vp[(size_t)t * 3 * C_];
        float z = p * logf(fmaxf(fabsf(v + SHIFT_), V_MIN_));
        lm = fmaxf(lm, z);
    }
    __shared__ float red[4][64];
    red[r][col] = lm;
    __syncthreads();
    if (threadIdx.x < 64) {
        float m = fmaxf(fmaxf(red[0][threadIdx.x], red[1][threadIdx.x]),
                        fmaxf(red[2][threadIdx.x], red[3][threadIdx.x]));
        zmax[b * C_ + threadIdx.x + ctile * 64] = m;
    }
}

// ---------------------------------------------------------------------------
// prep_kv: one-shot K/V preparation per (b,h,t-tile) (unchanged from R5).
// ---------------------------------------------------------------------------
__global__ __launch_bounds__(256)
void prep_kv(const float* __restrict__ qkv, const float* __restrict__ p_param,
             const float* __restrict__ zmax,
             ushort_t* __restrict__ kbf, ushort_t* __restrict__ vtbf) {
    __shared__ ushort_t VtL[64 * 72];

    const int blk = blockIdx.x;
    const int tt = blk & 31;
    const int bh = blk >> 5;
    const int b = bh >> 4;
    const int h = bh & 15;
    const int t0 = tt * 64;

    const int tl = threadIdx.x >> 2;
    const int c0 = (threadIdx.x & 3) * 16;
    const int g0 = c0 >> 3;

    const size_t rowbase = (size_t)b * T_ * 3 * C_ + (size_t)(t0 + tl) * 3 * C_ + h * D_;

    // ---- K: convert to bf16, swizzled ----
    {
        const float* ksrc = qkv + rowbase + C_ + c0;
        ushort_t tk[16];
#pragma unroll
        for (int u = 0; u < 16; u += 4) {
            float4 f = *(const float4*)&ksrc[u];
            tk[u + 0] = f2bf(f.x); tk[u + 1] = f2bf(f.y);
            tk[u + 2] = f2bf(f.z); tk[u + 3] = f2bf(f.w);
        }
        size_t krow = ((size_t)bh * T_ + t0 + tl) * 64;
        *(s16x8*)&kbf[krow + ((g0)     ^ (tl & 7)) * 8] = *(s16x8*)&tk[0];
        *(s16x8*)&kbf[krow + ((g0 + 1) ^ (tl & 7)) * 8] = *(s16x8*)&tk[8];
    }

    // ---- V: GeM transform, transpose via LDS, swizzled ----
    {
        const float* vsrc = qkv + rowbase + 2 * C_ + c0;
#pragma unroll
        for (int u = 0; u < 16; u += 4) {
            float4 f = *(const float4*)&vsrc[u];
            float vv[4] = {f.x, f.y, f.z, f.w};
#pragma unroll
            for (int q = 0; q < 4; ++q) {
                int c = h * D_ + c0 + u + q;
                float p = clamp_p(p_param[c]);
                float z = p * __logf(fmaxf(fabsf(vv[q] + SHIFT_), V_MIN_));
                float val = __expf(z - zmax[b * C_ + c]);
                VtL[(c0 + u + q) * 72 + tl] = f2bf(val);
            }
        }
    }
    __syncthreads();
    {
        const int d = tl;
        s16x8 r0 = *(const s16x8*)&VtL[d * 72 + c0];
        s16x8 r1 = *(const s16x8*)&VtL[d * 72 + c0 + 8];
        size_t vbase = ((size_t)bh * 32 + tt) * 4096 + (size_t)d * 64;
        *(s16x8*)&vtbf[vbase + ((g0)     ^ (d & 7)) * 8] = r0;
        *(s16x8*)&vtbf[vbase + ((g0 + 1) ^ (d & 7)) * 8] = r1;
    }
}

// ---------------------------------------------------------------------------
// Flash attention, split-K by kt parity. 2048 blocks = bh(32) x par(2) x qt(32).
// Q A-frags held in registers (no Qs LDS, no Q barrier). K/V staged via
// global_load_lds. Partial (unnormalized) O written into the dead K/V planes
// of qkv (K plane = part 0, V plane = part 1); (m, l) to ml[part][bh][t].
// LDS = 8 + 8 + 9 KB -> 6 blocks/CU.
// ---------------------------------------------------------------------------
__global__ __launch_bounds__(256)
void attn_mfma(float* qkv,
               const ushort_t* __restrict__ kbf, const ushort_t* __restrict__ vtbf,
               float2* __restrict__ ml) {
    __shared__ ushort_t Ks[64 * 64];
    __shared__ ushort_t Vt[64 * 64];
    __shared__ ushort_t Ps[4][16 * 72];

    const int tid = threadIdx.x;
    const int w = tid >> 6;
    const int lane = tid & 63;
    const int l16 = lane & 15;
    const int quad = lane >> 4;

    const int qt = 31 - (blockIdx.x & 31);   // heavy tiles first
    const int par = (blockIdx.x >> 5) & 1;
    const int bh = blockIdx.x >> 6;
    const int b = bh >> 4;
    const int h = bh & 15;
    const int q0 = qt * 64;

    // swizzled group offsets for fragment reads (k-step 0/1)
    const int sg0 = ((0 + quad) ^ (l16 & 7)) * 8;
    const int sg1 = ((4 + quad) ^ (l16 & 7)) * 8;

    f32x4 O[4] = {};
    float m_i[4], l_i[4];
#pragma unroll
    for (int r = 0; r < 4; ++r) { m_i[r] = -INFINITY; l_i[r] = 0.f; }

    if (par <= qt) {
        // ---- Q A-frags in registers (pre-scaled by 1/8) ----
        s16x8 qf[2];
        {
            const int qrow = q0 + w * 16 + l16;
            const float* qrp = qkv + (size_t)b * T_ * 3 * C_
                             + (size_t)qrow * 3 * C_ + h * D_;
#pragma unroll
            for (int ks = 0; ks < 2; ++ks) {
                float4 f0 = *(const float4*)&qrp[ks * 32 + quad * 8];
                float4 f1 = *(const float4*)&qrp[ks * 32 + quad * 8 + 4];
                ushort_t t8[8];
                t8[0] = f2bf(f0.x * 0.125f); t8[1] = f2bf(f0.y * 0.125f);
                t8[2] = f2bf(f0.z * 0.125f); t8[3] = f2bf(f0.w * 0.125f);
                t8[4] = f2bf(f1.x * 0.125f); t8[5] = f2bf(f1.y * 0.125f);
                t8[6] = f2bf(f1.z * 0.125f); t8[7] = f2bf(f1.w * 0.125f);
                qf[ks] = *(s16x8*)t8;
            }
        }

        const ushort_t* khead = kbf + (size_t)bh * T_ * 64;
        const ushort_t* vhead = vtbf + (size_t)bh * 32 * 4096;

        for (int kt = par; kt <= qt; kt += 2) {
            __syncthreads();
            {
                const ushort_t* ktile = khead + (size_t)kt * 4096;
                const ushort_t* vtile = vhead + (size_t)kt * 4096;
#pragma unroll
                for (int i = 0; i < 2; ++i) {
                    int off = (tid + i * 256) * 8;
                    gload_lds16(&ktile[off], &Ks[off]);
                    gload_lds16(&vtile[off], &Vt[off]);
                }
            }
            __syncthreads();

            // ---- S = Q K^T ----
            f32x4 s[4] = {};
#pragma unroll
            for (int ks = 0; ks < 2; ++ks) {
                const int sg = ks ? sg1 : sg0;
#pragma unroll
                for (int nt = 0; nt < 4; ++nt) {
                    s16x8 bfr = *(const s16x8*)&Ks[(nt * 16 + l16) * 64 + sg];
                    s[nt] = __builtin_amdgcn_mfma_f32_16x16x32_bf16(qf[ks], bfr, s[nt], 0, 0, 0);
                }
            }

            // ---- causal mask (diag tile only) ----
            if (kt == qt) {
#pragma unroll
                for (int nt = 0; nt < 4; ++nt) {
                    int col = nt * 16 + l16;
#pragma unroll
                    for (int r = 0; r < 4; ++r) {
                        int row = w * 16 + quad * 4 + r;
                        if (col > row) s[nt][r] = -3.0e38f;
                    }
                }
            }

            // ---- online softmax ----
#pragma unroll
            for (int r = 0; r < 4; ++r) {
                float mx = fmaxf(fmaxf(s[0][r], s[1][r]), fmaxf(s[2][r], s[3][r]));
                mx = fmaxf(mx, __shfl_xor(mx, 1));
                mx = fmaxf(mx, __shfl_xor(mx, 2));
                mx = fmaxf(mx, __shfl_xor(mx, 4));
                mx = fmaxf(mx, __shfl_xor(mx, 8));
                float mnew = fmaxf(m_i[r], mx);
                float sc = __expf(m_i[r] - mnew);
                m_i[r] = mnew;
                float rs = 0.f;
                unsigned short pb[4];
#pragma unroll
                for (int nt = 0; nt < 4; ++nt) {
                    float p = __expf(s[nt][r] - mnew);
                    rs += p;
                    pb[nt] = f2bf(p);
                }
                rs += __shfl_xor(rs, 1);
                rs += __shfl_xor(rs, 2);
                rs += __shfl_xor(rs, 4);
                rs += __shfl_xor(rs, 8);
                l_i[r] = l_i[r] * sc + rs;
#pragma unroll
                for (int nt = 0; nt < 4; ++nt) {
                    O[nt][r] *= sc;
                    Ps[w][(quad * 4 + r) * 72 + nt * 16 + l16] = pb[nt];
                }
            }

            // ---- O += P V ----
#pragma unroll
            for (int ks = 0; ks < 2; ++ks) {
                const int sg = ks ? sg1 : sg0;
                s16x8 afr = *(const s16x8*)&Ps[w][l16 * 72 + ks * 32 + quad * 8];
#pragma unroll
                for (int nt = 0; nt < 4; ++nt) {
                    s16x8 bfr = *(const s16x8*)&Vt[(nt * 16 + l16) * 64 + sg];
                    O[nt] = __builtin_amdgcn_mfma_f32_16x16x32_bf16(afr, bfr, O[nt], 0, 0, 0);
                }
            }
        }
    }

    // ---- write partials: O (unnormalized) into K/V plane of qkv; (m,l) to ml ----
#pragma unroll
    for (int r = 0; r < 4; ++r) {
        int t = q0 + w * 16 + quad * 4 + r;
        float* dst = qkv + (size_t)(b * T_ + t) * 3 * C_ + (1 + par) * C_ + h * D_;
#pragma unroll
        for (int nt = 0; nt < 4; ++nt)
            dst[nt * 16 + l16] = O[nt][r];
        if (l16 == 0)
            ml[(par * 32 + bh) * T_ + t] = make_float2(m_i[r], l_i[r]);
    }
}

// ---------------------------------------------------------------------------
// combine_y: merge 2 split-K partials, inverse power transform, hi/lo split.
// ---------------------------------------------------------------------------
__global__ __launch_bounds__(256)
void combine_y(const float* __restrict__ qkv, const float* __restrict__ p_param,
               const float* __restrict__ zmax, const float2* __restrict__ ml,
               ushort_t* __restrict__ yh, ushort_t* __restrict__ yl) {
    int idx = blockIdx.x * 256 + threadIdx.x;    // one per 4 elements
    int n4 = idx * 4;
    int c = n4 & (C_ - 1);
    int bt = n4 >> 10;
    int t = bt & (T_ - 1);
    int b = bt >> 11;
    int h = c >> 6;
    int bh = b * H_ + h;

    float2 ml0 = ml[bh * T_ + t];
    float2 ml1 = ml[(32 + bh) * T_ + t];
    float m = fmaxf(ml0.x, ml1.x);
    float w0 = __expf(ml0.x - m), w1 = __expf(ml1.x - m);
    float inv_den = 1.f / (w0 * ml0.y + w1 * ml1.y);

    const float* base = qkv + (size_t)bt * 3 * C_;
    float4 O0 = *(const float4*)&base[C_ + c];
    float4 O1 = *(const float4*)&base[2 * C_ + c];
    float4 zm = *(const float4*)&zmax[b * C_ + c];
    float4 pp = *(const float4*)&p_param[c];

    ushort4 hh, ll;
    {
        float mean = (w0 * O0.x + w1 * O1.x) * inv_den;
        float y = expf((zm.x + logf(mean)) / clamp_p(pp.x)) - SHIFT_;
        hh.x = f2bf(y); ll.x = f2bf(y - bf2f(hh.x));
    }
    {
        float mean = (w0 * O0.y + w1 * O1.y) * inv_den;
        float y = expf((zm.y + logf(mean)) / clamp_p(pp.y)) - SHIFT_;
        hh.y = f2bf(y); ll.y = f2bf(y - bf2f(hh.y));
    }
    {
        float mean = (w0 * O0.z + w1 * O1.z) * inv_den;
        float y = expf((zm.z + logf(mean)) / clamp_p(pp.z)) - SHIFT_;
        hh.z = f2bf(y); ll.z = f2bf(y - bf2f(hh.z));
    }
    {
        float mean = (w0 * O0.w + w1 * O1.w) * inv_den;
        float y = expf((zm.w + logf(mean)) / clamp_p(pp.w)) - SHIFT_;
        hh.w = f2bf(y); ll.w = f2bf(y - bf2f(hh.w));
    }
    ((ushort4*)yh)[idx] = hh;
    ((ushort4*)yl)[idx] = ll;
}

// ---------------------------------------------------------------------------
extern "C" void kernel_launch(void* const* d_in, const int* in_sizes, int n_in,
                              void* d_out, int out_size, void* d_ws, size_t ws_size,
                              hipStream_t stream) {
    const float* x      = (const float*)d_in[0];
    const float* w_attn = (const float*)d_in[1];
    const float* b_attn = (const float*)d_in[2];
    const float* w_proj = (const float*)d_in[3];
    const float* b_proj = (const float*)d_in[4];
    const float* p_par  = (const float*)d_in[5];
    float* out = (float*)d_out;

    char* ws = (char*)d_ws;
    float* qkv = (float*)ws;                                  // M x 3C fp32
    char* p1 = ws + (size_t)M_ * 3 * C_ * sizeof(float);
    ushort_t* xh = (ushort_t*)p1;                             // M x C bf16 (aliases yh)
    ushort_t* xl = xh + (size_t)M_ * C_;                      // (aliases yl)
    ushort_t* wth = xl + (size_t)M_ * C_;                     // 3C x C bf16
    ushort_t* wtl = wth + (size_t)3 * C_ * C_;
    float* zmax = (float*)(wtl + (size_t)3 * C_ * C_);        // B x C
    ushort_t* kbf  = (ushort_t*)((char*)zmax + B_ * C_ * sizeof(float));  // BH x T x 64
    ushort_t* vtbf = kbf + (size_t)B_ * H_ * T_ * 64;                     // BH x 32 x 64 x 64
    float2* ml = (float2*)(vtbf + (size_t)B_ * H_ * T_ * 64);             // 2 x 32 x T

    // 1) split x -> hi/lo bf16
    conv_hilo<<<M_ * C_ / 1024, 256, 0, stream>>>(x, xh, xl);
    // 2) transpose+split w_attn -> [3C][C]
    convT_hilo<<<dim3(3 * C_ / 64, C_ / 64), 256, 0, stream>>>(w_attn, wth, wtl, 3 * C_, C_);
    // 3) qkv = x @ w_attn + b_attn  (bf16x3 MFMA)
    gemm3<<<dim3(3 * C_ / 128, M_ / 128), 256, 0, stream>>>(xh, xl, wth, wtl,
                                                            b_attn, qkv, M_, 3 * C_, C_);
    // 4) z_max over T per (b,c)
    zmax_kernel<<<B_ * (C_ / 64), 256, 0, stream>>>(qkv, p_par, zmax);
    // 5) prep K (bf16 swizzled) + V (GeM transform, transposed, swizzled)
    prep_kv<<<B_ * H_ * 32, 256, 0, stream>>>(qkv, p_par, zmax, kbf, vtbf);
    // 6) split-K MFMA flash attention -> partials in qkv K/V planes + ml
    attn_mfma<<<B_ * H_ * (T_ / 64) * 2, 256, 0, stream>>>(qkv, kbf, vtbf, ml);
    // 7) combine partials + y transform -> yh/yl (alias xh/xl)
    combine_y<<<M_ * C_ / 1024, 256, 0, stream>>>(qkv, p_par, zmax, ml, xh, xl);
    // 8) transpose+split w_proj -> [C][C]
    convT_hilo<<<dim3(C_ / 64, C_ / 64), 256, 0, stream>>>(w_proj, wth, wtl, C_, C_);
    // 9) out = y @ w_proj + b_proj  (bf16x3 MFMA)
    gemm3<<<dim3(C_ / 128, M_ / 128), 256, 0, stream>>>(xh, xl, wth, wtl,
                                                        b_proj, out, M_, C_, C_);
}